// Round 9
// baseline (532.467 us; speedup 1.0000x reference)
//
#include <hip/hip_runtime.h>
#include <hip/hip_bf16.h>

#define B_  8
#define L_  4096
#define D_  2048
#define H_  16
#define HD_ 128
#define MK_ 1024
#define VTP 1040   // Vt row pitch (k dim, 1025 used + pad)

typedef __attribute__((ext_vector_type(8))) short short8;
typedef __attribute__((ext_vector_type(4))) float f32x4;

__device__ inline unsigned short f2bf(float f) {
  unsigned int u = __float_as_uint(f);
  unsigned int r = (u + 0x7fffu + ((u >> 16) & 1u)) >> 16;   // RNE
  return (unsigned short)r;
}

__device__ __forceinline__ void gload_lds16(const void* g, void* l) {
  __builtin_amdgcn_global_load_lds(
      (const __attribute__((address_space(1))) void*)g,
      (__attribute__((address_space(3))) void*)l, 16, 0, 0);
}

// ---------------------------------------------------------------- mask dtype
__global__ void detect_mask_kernel(const unsigned char* __restrict__ mask, int* flag) {
  __shared__ int cnt;
  if (threadIdx.x == 0) cnt = 0;
  __syncthreads();
  int local = 0;
  for (int i = threadIdx.x; i < B_ * L_; i += 256) local += (mask[i] != 0);
  atomicAdd(&cnt, local);
  __syncthreads();
  if (threadIdx.x == 0) {
    int t = 0;
    if (cnt == B_ * MK_)      t = 0; // u8 bool
    else if (cnt == 2 * MK_)  t = 1; // i32
    else if (cnt == 4 * MK_)  t = 2; // f32
    *flag = t;
  }
}

// ------------------------------------------------------- compaction / rowmap
__global__ void build_rowmap_kernel(const void* __restrict__ maskv,
                                    const int* __restrict__ flag,
                                    int* __restrict__ rowmap) {
  int b = blockIdx.x;
  int tid = threadIdx.x;
  int t = *flag;
  __shared__ int cnts[256];
  unsigned char loc[16];
  int c = 0;
  for (int j = 0; j < 16; ++j) {
    int pos = tid * 16 + j;
    int mv;
    if (t == 1)      mv = ((const int*)maskv)[b * L_ + pos] != 0;
    else if (t == 2) mv = ((const float*)maskv)[b * L_ + pos] != 0.0f;
    else             mv = ((const unsigned char*)maskv)[b * L_ + pos] != 0;
    loc[j] = (unsigned char)mv; c += mv;
  }
  cnts[tid] = c;
  __syncthreads();
  for (int off = 1; off < 256; off <<= 1) {
    int v = (tid >= off) ? cnts[tid - off] : 0;
    __syncthreads();
    cnts[tid] += v;
    __syncthreads();
  }
  int rank = cnts[tid] - c;
  for (int j = 0; j < 16; ++j) {
    if (loc[j]) {
      if (rank < MK_) rowmap[b * MK_ + rank] = b * L_ + tid * 16 + j;
      ++rank;
    }
  }
}

// ------------------------------------------------------------- gather + bf16
__global__ __launch_bounds__(256) void gather_sig_kernel(const float* __restrict__ x,
                                                         const int* __restrict__ rowmap,
                                                         unsigned short* __restrict__ sig) {
  int row = blockIdx.x;
  const float* src = x + (size_t)rowmap[row] * D_;
  unsigned short* dst = sig + (size_t)row * D_;
  int tid = threadIdx.x;
  float4 a = ((const float4*)src)[tid * 2];
  float4 b4 = ((const float4*)src)[tid * 2 + 1];
  uint4 o;
  o.x = f2bf(a.x)  | ((unsigned)f2bf(a.y)  << 16);
  o.y = f2bf(a.z)  | ((unsigned)f2bf(a.w)  << 16);
  o.z = f2bf(b4.x) | ((unsigned)f2bf(b4.y) << 16);
  o.w = f2bf(b4.z) | ((unsigned)f2bf(b4.w) << 16);
  *(uint4*)(dst + tid * 8) = o;
}

// ---------------------------------------------------------- f32 -> bf16 weights
__global__ __launch_bounds__(256) void conv_bf16_kernel(const float* __restrict__ W0,
                                                        const float* __restrict__ W1,
                                                        const float* __restrict__ W2,
                                                        const float* __restrict__ W3,
                                                        unsigned short* __restrict__ Wb) {
  const size_t per = (size_t)D_ * D_;
  int slab = blockIdx.x >> 11;
  const float* W = (slab == 0) ? W0 : (slab == 1) ? W1 : (slab == 2) ? W2 : W3;
  size_t i = ((size_t)(blockIdx.x & 2047) * 256 + threadIdx.x) * 8;
  float4 a = *(const float4*)(W + i);
  float4 b4 = *(const float4*)(W + i + 4);
  uint4 o;
  o.x = f2bf(a.x)  | ((unsigned)f2bf(a.y)  << 16);
  o.y = f2bf(a.z)  | ((unsigned)f2bf(a.w)  << 16);
  o.z = f2bf(b4.x) | ((unsigned)f2bf(b4.y) << 16);
  o.w = f2bf(b4.z) | ((unsigned)f2bf(b4.w) << 16);
  *(uint4*)(Wb + slab * per + i) = o;
}

// -------------------------------------------- register K/V rows (batched over b)
__global__ __launch_bounds__(256) void reg_kv_kernel(
    const float* __restrict__ reg, const float* __restrict__ Wrk, const float* __restrict__ brk,
    const float* __restrict__ Wrv, const float* __restrict__ brv,
    unsigned short* __restrict__ Kb, unsigned short* __restrict__ Vt) {
  int gw = (blockIdx.x * 256 + threadIdx.x) >> 6;  // 4096 waves
  int lane = threadIdx.x & 63;
  int mat = gw >> 11;
  int n = gw & 2047;
  const float* W = mat ? Wrv : Wrk;
  const float* wrow = W + (size_t)n * D_;
  float s[8] = {};
  for (int j = 0; j < 8; ++j) {
    int e = j * 256 + lane * 4;
    float4 wv = *(const float4*)(wrow + e);
#pragma unroll
    for (int b = 0; b < 8; ++b) {
      float4 rv = *(const float4*)(reg + (size_t)b * D_ + e);
      s[b] += wv.x * rv.x + wv.y * rv.y + wv.z * rv.z + wv.w * rv.w;
    }
  }
#pragma unroll
  for (int off = 32; off; off >>= 1)
#pragma unroll
    for (int b = 0; b < 8; ++b) s[b] += __shfl_down(s[b], off);
  if (lane == 0) {
    float bias = (mat ? brv : brk)[n];
#pragma unroll
    for (int b = 0; b < 8; ++b) {
      unsigned short v = f2bf(s[b] + bias);
      if (mat) {
        Vt[(((size_t)b * 16 + (n >> 7)) * 128 + (n & 127)) * VTP + 1024] = v;
      } else {
        Kb[((size_t)b * 1025 + 1024) * D_ + n] = v;
      }
    }
  }
}

// ------------------------------------------------- 256x256 deep-pipelined GEMM
// Register-pipelined fragments: each phase issues ds_reads for the NEXT MFMA
// cluster; counted lgkmcnt hides LDS latency under the current cluster.
// 2 barriers per K-tile. vmcnt(6) counted, 3-tile global lookahead.
template<int FUSED>
__global__ __launch_bounds__(512, 2) void gemm8_kernel(
    const unsigned short* __restrict__ A, const unsigned short* __restrict__ Bw,
    const float* __restrict__ b0, const float* __restrict__ b1, const float* __restrict__ b2,
    void* __restrict__ O0, void* __restrict__ O1, void* __restrict__ O2,
    const int* __restrict__ rowmap, float qalpha, int nbt, int matfix) {
  __shared__ __align__(16) unsigned short lds[4][2][8192];  // [buf][A/B][256 rows x 32 k]
  int tid = threadIdx.x, lane = tid & 63, w = tid >> 6;
  int g = lane >> 4, l15 = lane & 15;
  int wm = w >> 2, wn = w & 3;

  int bid = blockIdx.x;
  int xcd = bid & 7, j = bid >> 3;          // grid = 8 * (4 * nbt)
  int mb = xcd * 4 + j / nbt, nb = j % nbt;
  int m0 = mb * 256, n0 = nb * 256;

  f32x4 acc[2][4][4] = {};

#define STAGE(kt, c) {                                                          \
    const unsigned short* src0 = (c) ? Bw : A;                                  \
    int base0 = (c) ? n0 : m0;                                                  \
    int sg = (lane & 3) ^ ((lane >> 3) & 3);                                    \
    _Pragma("unroll")                                                           \
    for (int i_ = 0; i_ < 2; ++i_) {                                            \
      int row = (w * 2 + i_) * 16 + (lane >> 2);                                \
      gload_lds16(src0 + (size_t)(base0 + row) * D_ + (kt) * 32 + sg * 8,       \
                  &lds[(kt) & 3][c][(w * 2 + i_) * 512]);                       \
    }                                                                           \
  }

  // prologue: 3-tile lead
  STAGE(0, 0); STAGE(0, 1);
  STAGE(1, 0); STAGE(1, 1);
  STAGE(2, 0); STAGE(2, 1);
  asm volatile("s_waitcnt vmcnt(8)" ::: "memory");   // tile 0 landed (own loads)
  __builtin_amdgcn_s_barrier();                      // all waves' tile 0 landed

  int sw8 = (g ^ ((l15 >> 1) & 3)) * 8;              // swizzled 16B slot (ushort units)

  short8 afE[4], afO[4], bfA[4], bfB[4];
  // preload frags for kt=0 phase0 (buffer 0): bfA + afE(half0)
  {
    const unsigned short* Ab = &lds[0][0][0];
    const unsigned short* Bb = &lds[0][1][0];
#pragma unroll
    for (int nf = 0; nf < 4; ++nf)
      bfA[nf] = *(const short8*)(Bb + (wn * 64 + nf * 16 + l15) * 32 + sw8);
#pragma unroll
    for (int mf = 0; mf < 4; ++mf)
      afE[mf] = *(const short8*)(Ab + (wm * 128 + mf * 16 + l15) * 32 + sw8);
  }

  // one K-tile: ph0 {issue afO; STAGE-A; lgkm(4); MFMA0} ;
  //             ph1 {vmcnt; barrier; issue next bf/afE; STAGE-B; lgkm(8); MFMA1; barrier}
#define KTILE(kt, bfC, bfN)                                                       \
  {                                                                               \
    const unsigned short* Abuf = &lds[(kt) & 3][0][0];                            \
    _Pragma("unroll")                                                             \
    for (int mf = 0; mf < 4; ++mf)                                                \
      afO[mf] = *(const short8*)(Abuf + (wm * 128 + 64 + mf * 16 + l15) * 32 + sw8); \
    if ((kt) + 3 < 64) STAGE((kt) + 3, 0);                                        \
    asm volatile("s_waitcnt lgkmcnt(4)" ::: "memory");                            \
    __builtin_amdgcn_sched_barrier(0);                                            \
    __builtin_amdgcn_s_setprio(1);                                                \
    _Pragma("unroll")                                                             \
    for (int mf = 0; mf < 4; ++mf)                                                \
      _Pragma("unroll")                                                           \
      for (int nf = 0; nf < 4; ++nf)                                              \
        acc[0][mf][nf] = __builtin_amdgcn_mfma_f32_16x16x32_bf16(afE[mf], bfC[nf], acc[0][mf][nf], 0, 0, 0); \
    __builtin_amdgcn_s_setprio(0);                                                \
    if ((kt) <= 60)      asm volatile("s_waitcnt vmcnt(6)" ::: "memory");         \
    else if ((kt) == 61) asm volatile("s_waitcnt vmcnt(4)" ::: "memory");         \
    else if ((kt) == 62) asm volatile("s_waitcnt vmcnt(0)" ::: "memory");         \
    if ((kt) < 63) {                                                              \
      __builtin_amdgcn_s_barrier();                                               \
      const unsigned short* An = &lds[((kt) + 1) & 3][0][0];                      \
      const unsigned short* Bn = &lds[((kt) + 1) & 3][1][0];                      \
      _Pragma("unroll")                                                           \
      for (int nf = 0; nf < 4; ++nf)                                              \
        bfN[nf] = *(const short8*)(Bn + (wn * 64 + nf * 16 + l15) * 32 + sw8);    \
      _Pragma("unroll")                                                           \
      for (int mf = 0; mf < 4; ++mf)                                              \
        afE[mf] = *(const short8*)(An + (wm * 128 + mf * 16 + l15) * 32 + sw8);   \
      if ((kt) + 3 < 64) STAGE((kt) + 3, 1);                                      \
      asm volatile("s_waitcnt lgkmcnt(8)" ::: "memory");                          \
    } else {                                                                      \
      asm volatile("s_waitcnt lgkmcnt(0)" ::: "memory");                          \
    }                                                                             \
    __builtin_amdgcn_sched_barrier(0);                                            \
    __builtin_amdgcn_s_setprio(1);                                                \
    _Pragma("unroll")                                                             \
    for (int mf = 0; mf < 4; ++mf)                                                \
      _Pragma("unroll")                                                           \
      for (int nf = 0; nf < 4; ++nf)                                              \
        acc[1][mf][nf] = __builtin_amdgcn_mfma_f32_16x16x32_bf16(afO[mf], bfC[nf], acc[1][mf][nf], 0, 0, 0); \
    __builtin_amdgcn_s_setprio(0);                                                \
    if ((kt) < 63) __builtin_amdgcn_s_barrier();                                  \
  }

  for (int kt2 = 0; kt2 < 32; ++kt2) {
    KTILE(2 * kt2,     bfA, bfB);
    KTILE(2 * kt2 + 1, bfB, bfA);
  }
#undef KTILE
#undef STAGE

  int mat = 0;
  const float* bias = b0;
  float alpha = 1.0f;
  int n0l = n0;
  if (FUSED) {
    mat = (matfix >= 0) ? matfix : (n0 >> 11);
    bias = (mat == 0) ? b0 : ((mat == 1) ? b1 : b2);
    alpha = (mat == 0) ? qalpha : 1.0f;
    n0l = n0 & 2047;
  }

#pragma unroll
  for (int ph = 0; ph < 2; ++ph) {
#pragma unroll
    for (int mf = 0; mf < 4; ++mf) {
#pragma unroll
      for (int nf = 0; nf < 4; ++nf) {
        int nn = n0l + wn * 64 + nf * 16 + l15;
        float bvv = bias[nn];
        int m = m0 + wm * 128 + ph * 64 + mf * 16 + g * 4;
        if (FUSED) {
          if (mat == 2) {                      // V -> transposed Vt
            int bb = m >> 10, tok = m & 1023;
            size_t base = (((size_t)bb * 16 + (nn >> 7)) * 128 + (nn & 127)) * VTP + tok;
            uint2 u;
            u.x = f2bf(acc[ph][mf][nf][0] + bvv) | ((unsigned)f2bf(acc[ph][mf][nf][1] + bvv) << 16);
            u.y = f2bf(acc[ph][mf][nf][2] + bvv) | ((unsigned)f2bf(acc[ph][mf][nf][3] + bvv) << 16);
            *(uint2*)((unsigned short*)O2 + base) = u;
          } else {
            unsigned short* out = (mat == 0) ? (unsigned short*)O0 : (unsigned short*)O1;
#pragma unroll
            for (int r = 0; r < 4; ++r) {
              float v = (acc[ph][mf][nf][r] + bvv) * alpha;
              int mm = m + r;
              int row = (mat == 1) ? mm + (mm >> 10) : mm;
              out[(size_t)row * D_ + nn] = f2bf(v);
            }
          }
        } else {
#pragma unroll
          for (int r = 0; r < 4; ++r) {
            int row = rowmap[m + r];
            ((float*)O0)[(size_t)row * D_ + nn] = acc[ph][mf][nf][r] + bvv;
          }
        }
      }
    }
  }
}

// ----------------------------------------------------------- flash attention
// Single-buffer K, 50 KB LDS -> 3 blocks/CU. K(t+1) prefetch moved EARLY: a
// barrier right after the QK cluster (all Ks reads are in registers by then)
// lets K(t+1) stage under softmax+stores+PV -> lead ~700+ cyc >= HBM latency.
// vmcnt ledger (issue order: K(t+1) oldest -> stores(t-1) -> copies(t) -> V(t)):
//   head wait vmcnt(10) (t=0: 6)  — retires only K; stores stay in flight
//   mid  wait vmcnt(2)  (last: 0) — retires stores+copies+V; K(t+1) stays out
__device__ __forceinline__ void stage_k(const unsigned short* Kbase, unsigned short* dst,
                                        int kv0, int w, int lane) {
#pragma unroll
  for (int i = 0; i < 2; ++i) {
    int ib = w * 2 + i;
    int row = ib * 4 + (lane >> 4);
    int sl = (lane & 15) ^ (row & 7);
    int krow = kv0 + row; if (krow > MK_) krow = MK_;
    gload_lds16(Kbase + (size_t)krow * D_ + sl * 8, dst + ib * 512);
  }
}
__device__ __forceinline__ void stage_v(const unsigned short* Vbase, unsigned short* dst,
                                        int kv0, int w, int lane) {
#pragma unroll
  for (int i = 0; i < 2; ++i) {
    int ib = w * 2 + i;
    int row = ib * 8 + (lane >> 3);
    int sl = (lane & 7) ^ (row & 7);
    gload_lds16(Vbase + (size_t)row * VTP + kv0 + sl * 8, dst + ib * 512);
  }
}

#define NF4 16777216   // total float4 in x (8*4096*2048/4)

__global__ __launch_bounds__(512) void attn_kernel(
    const unsigned short* __restrict__ Qb, const unsigned short* __restrict__ Kb,
    const unsigned short* __restrict__ Vt, unsigned short* __restrict__ Ob,
    const float4* __restrict__ xsrc, float4* __restrict__ xdst) {
  int bx = blockIdx.x;
  int gq = bx >> 7;                // 0 = heaviest
  int qi = 7 - gq;
  int bh = bx & 127;
  int b = bh >> 4, h = bh & 15;
  int tid = threadIdx.x, lane = tid & 63, w = tid >> 6;
  int g = lane >> 4, l15 = lane & 15;
  int q0 = qi * 128;
  int nt = 2 * qi + 3;             // causal tiles + register tile

  // copy quota: this block's float4 range start (4 f4/thread/iter)
  size_t cpyBase = ((size_t)128 * (18 * gq - gq * gq) + (size_t)(bx & 127) * nt) * 2048;

  __shared__ __align__(16) unsigned short Ks[64 * 128];   // 16 KB, single buffer
  __shared__ __align__(16) unsigned short Vts[128 * 64];  // 16 KB
  __shared__ __align__(16) unsigned short Ps[8][16][72];  // 18 KB

  const unsigned short* Kbase = Kb + (size_t)b * 1025 * D_ + h * HD_;
  const unsigned short* Vbase = Vt + (size_t)bh * 128 * VTP;

  short8 qf[4];
  {
    const unsigned short* qrow = Qb + (size_t)(b * MK_ + q0 + w * 16 + l15) * D_ + h * HD_;
#pragma unroll
    for (int kk = 0; kk < 4; ++kk) qf[kk] = *(const short8*)(qrow + kk * 32 + g * 8);
  }

  f32x4 oacc[8] = {};
  float mrow[4], lrow[4];
#pragma unroll
  for (int r = 0; r < 4; ++r) { mrow[r] = -__builtin_inff(); lrow[r] = 0.f; }

  int qminw = q0 + w * 16;

  stage_k(Kbase, Ks, 0, w, lane);   // prologue: K(0)

  for (int t = 0; t < nt; ++t) {
    int kv0 = (t < nt - 1) ? t * 64 : MK_;

    // ---- copy loads (always exactly 4, clamped) ----
    size_t ci[4];
    float4 cv[4];
    {
      size_t i0 = cpyBase + (size_t)t * 2048 + tid;
#pragma unroll
      for (int jj = 0; jj < 4; ++jj) {
        size_t ix = i0 + jj * 512;
        ci[jj] = ix < NF4 ? ix : (NF4 - 1);
        cv[jj] = xsrc[ci[jj]];
      }
    }

    stage_v(Vbase, Vts, kv0, w, lane);
    // head wait: retire ONLY K(t); stores/copies/V stay in flight
    if (t == 0) asm volatile("s_waitcnt vmcnt(6)" ::: "memory");
    else        asm volatile("s_waitcnt vmcnt(10)" ::: "memory");
    __builtin_amdgcn_s_barrier();    // barrier 1: Ks(t) visible to all waves

    bool active = (t == nt - 1) || (t * 64 <= qminw + 15);
    f32x4 sacc[4] = {};
    if (active) {
      __builtin_amdgcn_s_setprio(1);
#pragma unroll
      for (int kk = 0; kk < 4; ++kk) {
#pragma unroll
        for (int nf = 0; nf < 4; ++nf) {
          int krow = nf * 16 + l15;
          int sw = (kk * 4 + g) ^ (krow & 7);
          short8 kf = *(const short8*)(Ks + krow * 128 + sw * 8);
          sacc[nf] = __builtin_amdgcn_mfma_f32_16x16x32_bf16(qf[kk], kf, sacc[nf], 0, 0, 0);
        }
      }
      __builtin_amdgcn_s_setprio(0);
    }

    __builtin_amdgcn_s_barrier();    // barrier 1.5: all Ks reads in registers
    // EARLY K(t+1) prefetch: stages under softmax + stores + PV (long lead)
    if (t + 1 < nt) {
      int kv1 = (t + 1 < nt - 1) ? (t + 1) * 64 : MK_;
      stage_k(Kbase, Ks, kv1, w, lane);
    }

    if (active) {
      if (t == nt - 1) {
#pragma unroll
        for (int nf = 0; nf < 4; ++nf) {
          int col = nf * 16 + l15;
          if (col != 0) {
#pragma unroll
            for (int r = 0; r < 4; ++r) sacc[nf][r] = -1e9f;
          }
        }
      } else if (t * 64 + 63 > qminw) {
        int qb = qminw - t * 64 + g * 4;
#pragma unroll
        for (int nf = 0; nf < 4; ++nf) {
          int col = nf * 16 + l15;
#pragma unroll
          for (int r = 0; r < 4; ++r)
            if (col > qb + r) sacc[nf][r] = -1e9f;
        }
      }

      // softmax (log2 domain, defer-max)
      float pm[4]; bool need = false;
#pragma unroll
      for (int r = 0; r < 4; ++r) {
        float mx = fmaxf(fmaxf(sacc[0][r], sacc[1][r]), fmaxf(sacc[2][r], sacc[3][r]));
        mx = fmaxf(mx, __shfl_xor(mx, 1));
        mx = fmaxf(mx, __shfl_xor(mx, 2));
        mx = fmaxf(mx, __shfl_xor(mx, 4));
        mx = fmaxf(mx, __shfl_xor(mx, 8));
        pm[r] = mx;
        need |= (mx > mrow[r] + 8.0f);
      }
      if (__any((int)need)) {
#pragma unroll
        for (int r = 0; r < 4; ++r) {
          float mnew = fmaxf(mrow[r], pm[r]);
          float sf = exp2f(mrow[r] - mnew);
          mrow[r] = mnew;
          lrow[r] *= sf;
#pragma unroll
          for (int i = 0; i < 8; ++i) oacc[i][r] *= sf;
        }
      }
      float rs[4] = {0.f, 0.f, 0.f, 0.f};
#pragma unroll
      for (int nf = 0; nf < 4; ++nf) {
#pragma unroll
        for (int r = 0; r < 4; ++r) {
          float p = exp2f(sacc[nf][r] - mrow[r]);
          sacc[nf][r] = p;
          rs[r] += p;
        }
      }
#pragma unroll
      for (int r = 0; r < 4; ++r) {
        float s = rs[r];
        s += __shfl_xor(s, 1);
        s += __shfl_xor(s, 2);
        s += __shfl_xor(s, 4);
        s += __shfl_xor(s, 8);
        lrow[r] += s;
      }
#pragma unroll
      for (int nf = 0; nf < 4; ++nf)
#pragma unroll
        for (int r = 0; r < 4; ++r)
          Ps[w][g * 4 + r][nf * 16 + l15] = f2bf(sacc[nf][r]);
    }

    // mid wait: retire stores(t-1)+copies(t)+V(t); keep K(t+1) in flight
    if (t + 1 < nt) asm volatile("s_waitcnt vmcnt(2)" ::: "memory");
    else            asm volatile("s_waitcnt vmcnt(0)" ::: "memory");

    // ---- copy stores (copy loads retired by the wait above) ----
#pragma unroll
    for (int jj = 0; jj < 4; ++jj) xdst[ci[jj]] = cv[jj];

    __builtin_amdgcn_s_barrier();    // barrier 2: Vts ready (all waves)

    if (active) {
      __builtin_amdgcn_s_setprio(1);
#pragma unroll
      for (int kk = 0; kk < 2; ++kk) {
        short8 pf = *(const short8*)(&Ps[w][l15][kk * 32 + g * 8]);
#pragma unroll
        for (int nf = 0; nf < 8; ++nf) {
          int vrow = nf * 16 + l15;
          int sw = (kk * 4 + g) ^ (vrow & 7);
          short8 vf = *(const short8*)(Vts + vrow * 64 + sw * 8);
          oacc[nf] = __builtin_amdgcn_mfma_f32_16x16x32_bf16(pf, vf, oacc[nf], 0, 0, 0);
        }
      }
      __builtin_amdgcn_s_setprio(0);
    }
    __builtin_amdgcn_s_barrier();    // barrier 3: protect Vts/Ps overwrite next iter
  }

#pragma unroll
  for (int nf = 0; nf < 8; ++nf) {
#pragma unroll
    for (int r = 0; r < 4; ++r) {
      size_t row = (size_t)b * MK_ + q0 + w * 16 + g * 4 + r;
      Ob[row * D_ + h * HD_ + nf * 16 + l15] = f2bf(oacc[nf][r] / lrow[r]);
    }
  }
}

// ------------------------------------------------------------------- launch
extern "C" void kernel_launch(void* const* d_in, const int* in_sizes, int n_in,
                              void* d_out, int out_size, void* d_ws, size_t ws_size,
                              hipStream_t stream) {
  const float* x    = (const float*)d_in[0];
  const void*  mask = d_in[1];
  const float* reg  = (const float*)d_in[2];
  const float* Wq   = (const float*)d_in[3];
  const float* bq   = (const float*)d_in[4];
  const float* Wk   = (const float*)d_in[5];
  const float* bk   = (const float*)d_in[6];
  const float* Wv   = (const float*)d_in[7];
  const float* bv   = (const float*)d_in[8];
  const float* Wrk  = (const float*)d_in[9];
  const float* brk  = (const float*)d_in[10];
  const float* Wrv  = (const float*)d_in[11];
  const float* brv  = (const float*)d_in[12];
  const float* Wo   = (const float*)d_in[13];
  const float* bo   = (const float*)d_in[14];

  char* ws = (char*)d_ws;
  int* flag            = (int*)ws;                       // 256 B
  int* rowmap          = (int*)(ws + 256);               // 32768 B
  char* p = ws + 66048;
  unsigned short* sig = (unsigned short*)p;              p += (size_t)8192 * 2048 * 2;
  unsigned short* Qb  = (unsigned short*)p;              p += (size_t)8192 * 2048 * 2;
  unsigned short* Kb  = (unsigned short*)p;              p += (size_t)8200 * 2048 * 2;
  unsigned short* Vtb = (unsigned short*)p;              p += ((size_t)16384 * VTP + 64) * 2;
  unsigned short* Wbf = (unsigned short*)p;              // 33.6 MB fused / 8.4 MB fallback
  unsigned short* Ob  = sig;  // sig dead after QKV GEMM

  const size_t need_fused = (size_t)(p - ws) + (size_t)8192 * 2048 * 2;
  const bool fused = (ws_size >= need_fused);

  detect_mask_kernel<<<1, 256, 0, stream>>>((const unsigned char*)mask, flag);
  build_rowmap_kernel<<<8, 256, 0, stream>>>(mask, flag, rowmap);
  gather_sig_kernel<<<8192, 256, 0, stream>>>(x, rowmap, sig);
  reg_kv_kernel<<<1024, 256, 0, stream>>>(reg, Wrk, brk, Wrv, brv, Kb, Vtb);

  // fold 1/sqrt(HD) * log2(e) into Q so attn softmax uses exp2 directly
  const float qalpha = 0.08838834764831845f * 1.4426950408889634f;
  const size_t per = (size_t)2048 * 2048;

  if (fused) {
    conv_bf16_kernel<<<8192, 256, 0, stream>>>(Wq, Wk, Wv, Wo, Wbf);
    gemm8_kernel<1><<<768, 512, 0, stream>>>(sig, Wbf, bq, bk, bv, Qb, Kb, Vtb,
                                             nullptr, qalpha, 24, -1);
    attn_kernel<<<1024, 512, 0, stream>>>(Qb, Kb, Vtb, Ob, (const float4*)x, (float4*)d_out);
    gemm8_kernel<0><<<256, 512, 0, stream>>>(Ob, Wbf + 3 * per, bo, nullptr, nullptr,
                                             d_out, nullptr, nullptr, rowmap, 1.0f, 8, -1);
  } else {
    conv_bf16_kernel<<<2048, 256, 0, stream>>>(Wq, Wq, Wq, Wq, Wbf);
    gemm8_kernel<1><<<256, 512, 0, stream>>>(sig, Wbf, bq, bk, bv, Qb, Kb, Vtb,
                                             nullptr, qalpha, 8, 0);
    conv_bf16_kernel<<<2048, 256, 0, stream>>>(Wk, Wk, Wk, Wk, Wbf);
    gemm8_kernel<1><<<256, 512, 0, stream>>>(sig, Wbf, bq, bk, bv, Qb, Kb, Vtb,
                                             nullptr, qalpha, 8, 1);
    conv_bf16_kernel<<<2048, 256, 0, stream>>>(Wv, Wv, Wv, Wv, Wbf);
    gemm8_kernel<1><<<256, 512, 0, stream>>>(sig, Wbf, bq, bk, bv, Qb, Kb, Vtb,
                                             nullptr, qalpha, 8, 2);
    attn_kernel<<<1024, 512, 0, stream>>>(Qb, Kb, Vtb, Ob, (const float4*)x, (float4*)d_out);
    conv_bf16_kernel<<<2048, 256, 0, stream>>>(Wo, Wo, Wo, Wo, Wbf);
    gemm8_kernel<0><<<256, 512, 0, stream>>>(Ob, Wbf, bo, nullptr, nullptr,
                                             d_out, nullptr, nullptr, rowmap, 1.0f, 8, -1);
  }
}

// Round 10
// 531.982 us; speedup vs baseline: 1.0009x; 1.0009x over previous
//
#include <hip/hip_runtime.h>
#include <hip/hip_bf16.h>

#define B_  8
#define L_  4096
#define D_  2048
#define H_  16
#define HD_ 128
#define MK_ 1024
#define VTP 1040   // Vt row pitch (k dim, 1025 used + pad)

typedef __attribute__((ext_vector_type(8))) short short8;
typedef __attribute__((ext_vector_type(4))) float f32x4;

__device__ inline unsigned short f2bf(float f) {
  unsigned int u = __float_as_uint(f);
  unsigned int r = (u + 0x7fffu + ((u >> 16) & 1u)) >> 16;   // RNE
  return (unsigned short)r;
}

__device__ __forceinline__ void gload_lds16(const void* g, void* l) {
  __builtin_amdgcn_global_load_lds(
      (const __attribute__((address_space(1))) void*)g,
      (__attribute__((address_space(3))) void*)l, 16, 0, 0);
}

// ---------------------------------------------------------------- mask dtype
__global__ void detect_mask_kernel(const unsigned char* __restrict__ mask, int* flag) {
  __shared__ int cnt;
  if (threadIdx.x == 0) cnt = 0;
  __syncthreads();
  int local = 0;
  for (int i = threadIdx.x; i < B_ * L_; i += 256) local += (mask[i] != 0);
  atomicAdd(&cnt, local);
  __syncthreads();
  if (threadIdx.x == 0) {
    int t = 0;
    if (cnt == B_ * MK_)      t = 0; // u8 bool
    else if (cnt == 2 * MK_)  t = 1; // i32
    else if (cnt == 4 * MK_)  t = 2; // f32
    *flag = t;
  }
}

// ------------------------------------------------------- compaction / rowmap
__global__ void build_rowmap_kernel(const void* __restrict__ maskv,
                                    const int* __restrict__ flag,
                                    int* __restrict__ rowmap) {
  int b = blockIdx.x;
  int tid = threadIdx.x;
  int t = *flag;
  __shared__ int cnts[256];
  unsigned char loc[16];
  int c = 0;
  for (int j = 0; j < 16; ++j) {
    int pos = tid * 16 + j;
    int mv;
    if (t == 1)      mv = ((const int*)maskv)[b * L_ + pos] != 0;
    else if (t == 2) mv = ((const float*)maskv)[b * L_ + pos] != 0.0f;
    else             mv = ((const unsigned char*)maskv)[b * L_ + pos] != 0;
    loc[j] = (unsigned char)mv; c += mv;
  }
  cnts[tid] = c;
  __syncthreads();
  for (int off = 1; off < 256; off <<= 1) {
    int v = (tid >= off) ? cnts[tid - off] : 0;
    __syncthreads();
    cnts[tid] += v;
    __syncthreads();
  }
  int rank = cnts[tid] - c;
  for (int j = 0; j < 16; ++j) {
    if (loc[j]) {
      if (rank < MK_) rowmap[b * MK_ + rank] = b * L_ + tid * 16 + j;
      ++rank;
    }
  }
}

// ------------------------------------------------------------- gather + bf16
__global__ __launch_bounds__(256) void gather_sig_kernel(const float* __restrict__ x,
                                                         const int* __restrict__ rowmap,
                                                         unsigned short* __restrict__ sig) {
  int row = blockIdx.x;
  const float* src = x + (size_t)rowmap[row] * D_;
  unsigned short* dst = sig + (size_t)row * D_;
  int tid = threadIdx.x;
  float4 a = ((const float4*)src)[tid * 2];
  float4 b4 = ((const float4*)src)[tid * 2 + 1];
  uint4 o;
  o.x = f2bf(a.x)  | ((unsigned)f2bf(a.y)  << 16);
  o.y = f2bf(a.z)  | ((unsigned)f2bf(a.w)  << 16);
  o.z = f2bf(b4.x) | ((unsigned)f2bf(b4.y) << 16);
  o.w = f2bf(b4.z) | ((unsigned)f2bf(b4.w) << 16);
  *(uint4*)(dst + tid * 8) = o;
}

// ---------------------------------------------------------- f32 -> bf16 weights
__global__ __launch_bounds__(256) void conv_bf16_kernel(const float* __restrict__ W0,
                                                        const float* __restrict__ W1,
                                                        const float* __restrict__ W2,
                                                        const float* __restrict__ W3,
                                                        unsigned short* __restrict__ Wb) {
  const size_t per = (size_t)D_ * D_;
  int slab = blockIdx.x >> 11;
  const float* W = (slab == 0) ? W0 : (slab == 1) ? W1 : (slab == 2) ? W2 : W3;
  size_t i = ((size_t)(blockIdx.x & 2047) * 256 + threadIdx.x) * 8;
  float4 a = *(const float4*)(W + i);
  float4 b4 = *(const float4*)(W + i + 4);
  uint4 o;
  o.x = f2bf(a.x)  | ((unsigned)f2bf(a.y)  << 16);
  o.y = f2bf(a.z)  | ((unsigned)f2bf(a.w)  << 16);
  o.z = f2bf(b4.x) | ((unsigned)f2bf(b4.y) << 16);
  o.w = f2bf(b4.z) | ((unsigned)f2bf(b4.w) << 16);
  *(uint4*)(Wb + slab * per + i) = o;
}

// -------------------------------------------- register K/V rows (batched over b)
__global__ __launch_bounds__(256) void reg_kv_kernel(
    const float* __restrict__ reg, const float* __restrict__ Wrk, const float* __restrict__ brk,
    const float* __restrict__ Wrv, const float* __restrict__ brv,
    unsigned short* __restrict__ Kb, unsigned short* __restrict__ Vt) {
  int gw = (blockIdx.x * 256 + threadIdx.x) >> 6;  // 4096 waves
  int lane = threadIdx.x & 63;
  int mat = gw >> 11;
  int n = gw & 2047;
  const float* W = mat ? Wrv : Wrk;
  const float* wrow = W + (size_t)n * D_;
  float s[8] = {};
  for (int j = 0; j < 8; ++j) {
    int e = j * 256 + lane * 4;
    float4 wv = *(const float4*)(wrow + e);
#pragma unroll
    for (int b = 0; b < 8; ++b) {
      float4 rv = *(const float4*)(reg + (size_t)b * D_ + e);
      s[b] += wv.x * rv.x + wv.y * rv.y + wv.z * rv.z + wv.w * rv.w;
    }
  }
#pragma unroll
  for (int off = 32; off; off >>= 1)
#pragma unroll
    for (int b = 0; b < 8; ++b) s[b] += __shfl_down(s[b], off);
  if (lane == 0) {
    float bias = (mat ? brv : brk)[n];
#pragma unroll
    for (int b = 0; b < 8; ++b) {
      unsigned short v = f2bf(s[b] + bias);
      if (mat) {
        Vt[(((size_t)b * 16 + (n >> 7)) * 128 + (n & 127)) * VTP + 1024] = v;
      } else {
        Kb[((size_t)b * 1025 + 1024) * D_ + n] = v;
      }
    }
  }
}

// ------------------------------------------------- 256x256 BK=64 pipelined GEMM
// 2 LDS buffers (128 KB), 4 MFMA clusters of 16 per K-tile, ONE barrier + ONE
// vmcnt(0) per K-tile. Frag ds_reads pipelined cluster-to-cluster with counted
// lgkmcnt(4). Stages for tile kt+1 front-loaded at clusters 0 (A) and 1 (B);
// single end barrier provides both S(kt+1) visibility (after per-wave vmcnt(0))
// and WAR safety for buf[(kt+1)&1] (its reads landed by c3's lgkmcnt(0)).
template<int FUSED>
__global__ __launch_bounds__(512, 2) void gemm8_kernel(
    const unsigned short* __restrict__ A, const unsigned short* __restrict__ Bw,
    const float* __restrict__ b0, const float* __restrict__ b1, const float* __restrict__ b2,
    void* __restrict__ O0, void* __restrict__ O1, void* __restrict__ O2,
    const int* __restrict__ rowmap, float qalpha, int nbt, int matfix) {
  __shared__ __align__(16) unsigned short lds[2][2][16384];  // [buf][A/B][256 rows x 64 k]
  int tid = threadIdx.x, lane = tid & 63, w = tid >> 6;
  int g = lane >> 4, l15 = lane & 15;
  int wm = w >> 2, wn = w & 3;

  int bid = blockIdx.x;
  int xcd = bid & 7, j = bid >> 3;          // grid = 8 * (4 * nbt)
  int mb = xcd * 4 + j / nbt, nb = j % nbt;
  int m0 = mb * 256, n0 = nb * 256;

  f32x4 acc[2][4][4] = {};

  // per-thread staging constants: 4 x 16B chunks per matrix per K-tile
  size_t aoff[4], boff[4];
  int ldsoff[4];
#pragma unroll
  for (int i = 0; i < 4; ++i) {
    int chunk = tid + i * 512;
    int row = chunk >> 3;
    int gslot = (chunk & 7) ^ (row & 7);      // inverse-swizzled source slot
    aoff[i] = (size_t)(m0 + row) * D_ + gslot * 8;
    boff[i] = (size_t)(n0 + row) * D_ + gslot * 8;
    ldsoff[i] = (w * 64 + i * 512) * 8;       // wave-uniform dest; HW adds lane*16B
  }

#define STAGE_A(kt, BUF) {                                              \
    _Pragma("unroll")                                                   \
    for (int i_ = 0; i_ < 4; ++i_)                                      \
      gload_lds16(A + aoff[i_] + (kt) * 64, &lds[BUF][0][ldsoff[i_]]);  \
  }
#define STAGE_B(kt, BUF) {                                              \
    _Pragma("unroll")                                                   \
    for (int i_ = 0; i_ < 4; ++i_)                                      \
      gload_lds16(Bw + boff[i_] + (kt) * 64, &lds[BUF][1][ldsoff[i_]]); \
  }
#define RD_A(dst, BUF, h, kk) {                                         \
    _Pragma("unroll")                                                   \
    for (int mf_ = 0; mf_ < 4; ++mf_) {                                 \
      int r_ = wm * 128 + (h) * 64 + mf_ * 16 + l15;                    \
      dst[mf_] = *(const short8*)(&lds[BUF][0][r_ * 64 + (((kk) * 4 + g) ^ (r_ & 7)) * 8]); } \
  }
#define RD_B(dst, BUF, kk) {                                            \
    _Pragma("unroll")                                                   \
    for (int nf_ = 0; nf_ < 4; ++nf_) {                                 \
      int r_ = wn * 64 + nf_ * 16 + l15;                                \
      dst[nf_] = *(const short8*)(&lds[BUF][1][r_ * 64 + (((kk) * 4 + g) ^ (r_ & 7)) * 8]); } \
  }
#define MFMA16(h, af, bf) {                                             \
    _Pragma("unroll")                                                   \
    for (int mf_ = 0; mf_ < 4; ++mf_)                                   \
      _Pragma("unroll")                                                 \
      for (int nf_ = 0; nf_ < 4; ++nf_)                                 \
        acc[h][mf_][nf_] = __builtin_amdgcn_mfma_f32_16x16x32_bf16(af[mf_], bf[nf_], acc[h][mf_][nf_], 0, 0, 0); \
  }

  // prologue: stage tile 0, drain, barrier
  STAGE_A(0, 0); STAGE_B(0, 0);
  asm volatile("s_waitcnt vmcnt(0)" ::: "memory");
  __builtin_amdgcn_s_barrier();

  short8 afE[4], afO[4], bf0[4], bf1[4];

#define KTILE(kt, BUF)                                                    \
  {                                                                       \
    RD_B(bf0, BUF, 0); RD_B(bf1, BUF, 1); RD_A(afE, BUF, 0, 0);           \
    /* c0: half0/kk0 */                                                   \
    RD_A(afO, BUF, 0, 1);                                                 \
    if ((kt) + 1 < 32) STAGE_A((kt) + 1, BUF ^ 1);                        \
    asm volatile("s_waitcnt lgkmcnt(4)" ::: "memory");                    \
    __builtin_amdgcn_sched_barrier(0);                                    \
    __builtin_amdgcn_s_setprio(1);                                        \
    MFMA16(0, afE, bf0);                                                  \
    __builtin_amdgcn_s_setprio(0);                                        \
    /* c1: half0/kk1 */                                                   \
    RD_A(afE, BUF, 1, 0);                                                 \
    if ((kt) + 1 < 32) STAGE_B((kt) + 1, BUF ^ 1);                        \
    asm volatile("s_waitcnt lgkmcnt(4)" ::: "memory");                    \
    __builtin_amdgcn_sched_barrier(0);                                    \
    __builtin_amdgcn_s_setprio(1);                                        \
    MFMA16(0, afO, bf1);                                                  \
    __builtin_amdgcn_s_setprio(0);                                        \
    /* c2: half1/kk0 */                                                   \
    RD_A(afO, BUF, 1, 1);                                                 \
    asm volatile("s_waitcnt lgkmcnt(4)" ::: "memory");                    \
    __builtin_amdgcn_sched_barrier(0);                                    \
    __builtin_amdgcn_s_setprio(1);                                        \
    MFMA16(1, afE, bf0);                                                  \
    __builtin_amdgcn_s_setprio(0);                                        \
    /* c3: half1/kk1 */                                                   \
    asm volatile("s_waitcnt lgkmcnt(0)" ::: "memory");                    \
    __builtin_amdgcn_sched_barrier(0);                                    \
    __builtin_amdgcn_s_setprio(1);                                        \
    MFMA16(1, afO, bf1);                                                  \
    __builtin_amdgcn_s_setprio(0);                                        \
    asm volatile("s_waitcnt vmcnt(0)" ::: "memory");                      \
    __builtin_amdgcn_s_barrier();                                         \
  }

  for (int kt2 = 0; kt2 < 16; ++kt2) {
    KTILE(2 * kt2,     0);
    KTILE(2 * kt2 + 1, 1);
  }
#undef KTILE
#undef MFMA16
#undef RD_A
#undef RD_B
#undef STAGE_A
#undef STAGE_B

  int mat = 0;
  const float* bias = b0;
  float alpha = 1.0f;
  int n0l = n0;
  if (FUSED) {
    mat = (matfix >= 0) ? matfix : (n0 >> 11);
    bias = (mat == 0) ? b0 : ((mat == 1) ? b1 : b2);
    alpha = (mat == 0) ? qalpha : 1.0f;
    n0l = n0 & 2047;
  }

#pragma unroll
  for (int ph = 0; ph < 2; ++ph) {
#pragma unroll
    for (int mf = 0; mf < 4; ++mf) {
#pragma unroll
      for (int nf = 0; nf < 4; ++nf) {
        int nn = n0l + wn * 64 + nf * 16 + l15;
        float bvv = bias[nn];
        int m = m0 + wm * 128 + ph * 64 + mf * 16 + g * 4;
        if (FUSED) {
          if (mat == 2) {                      // V -> transposed Vt
            int bb = m >> 10, tok = m & 1023;
            size_t base = (((size_t)bb * 16 + (nn >> 7)) * 128 + (nn & 127)) * VTP + tok;
            uint2 u;
            u.x = f2bf(acc[ph][mf][nf][0] + bvv) | ((unsigned)f2bf(acc[ph][mf][nf][1] + bvv) << 16);
            u.y = f2bf(acc[ph][mf][nf][2] + bvv) | ((unsigned)f2bf(acc[ph][mf][nf][3] + bvv) << 16);
            *(uint2*)((unsigned short*)O2 + base) = u;
          } else {
            unsigned short* out = (mat == 0) ? (unsigned short*)O0 : (unsigned short*)O1;
#pragma unroll
            for (int r = 0; r < 4; ++r) {
              float v = (acc[ph][mf][nf][r] + bvv) * alpha;
              int mm = m + r;
              int row = (mat == 1) ? mm + (mm >> 10) : mm;
              out[(size_t)row * D_ + nn] = f2bf(v);
            }
          }
        } else {
#pragma unroll
          for (int r = 0; r < 4; ++r) {
            int row = rowmap[m + r];
            ((float*)O0)[(size_t)row * D_ + nn] = acc[ph][mf][nf][r] + bvv;
          }
        }
      }
    }
  }
}

// ----------------------------------------------------------- flash attention
// (unchanged from R9 — single-buffer K, early prefetch, fused x->out copy)
__device__ __forceinline__ void stage_k(const unsigned short* Kbase, unsigned short* dst,
                                        int kv0, int w, int lane) {
#pragma unroll
  for (int i = 0; i < 2; ++i) {
    int ib = w * 2 + i;
    int row = ib * 4 + (lane >> 4);
    int sl = (lane & 15) ^ (row & 7);
    int krow = kv0 + row; if (krow > MK_) krow = MK_;
    gload_lds16(Kbase + (size_t)krow * D_ + sl * 8, dst + ib * 512);
  }
}
__device__ __forceinline__ void stage_v(const unsigned short* Vbase, unsigned short* dst,
                                        int kv0, int w, int lane) {
#pragma unroll
  for (int i = 0; i < 2; ++i) {
    int ib = w * 2 + i;
    int row = ib * 8 + (lane >> 3);
    int sl = (lane & 7) ^ (row & 7);
    gload_lds16(Vbase + (size_t)row * VTP + kv0 + sl * 8, dst + ib * 512);
  }
}

#define NF4 16777216   // total float4 in x (8*4096*2048/4)

__global__ __launch_bounds__(512) void attn_kernel(
    const unsigned short* __restrict__ Qb, const unsigned short* __restrict__ Kb,
    const unsigned short* __restrict__ Vt, unsigned short* __restrict__ Ob,
    const float4* __restrict__ xsrc, float4* __restrict__ xdst) {
  int bx = blockIdx.x;
  int gq = bx >> 7;                // 0 = heaviest
  int qi = 7 - gq;
  int bh = bx & 127;
  int b = bh >> 4, h = bh & 15;
  int tid = threadIdx.x, lane = tid & 63, w = tid >> 6;
  int g = lane >> 4, l15 = lane & 15;
  int q0 = qi * 128;
  int nt = 2 * qi + 3;             // causal tiles + register tile

  size_t cpyBase = ((size_t)128 * (18 * gq - gq * gq) + (size_t)(bx & 127) * nt) * 2048;

  __shared__ __align__(16) unsigned short Ks[64 * 128];   // 16 KB, single buffer
  __shared__ __align__(16) unsigned short Vts[128 * 64];  // 16 KB
  __shared__ __align__(16) unsigned short Ps[8][16][72];  // 18 KB

  const unsigned short* Kbase = Kb + (size_t)b * 1025 * D_ + h * HD_;
  const unsigned short* Vbase = Vt + (size_t)bh * 128 * VTP;

  short8 qf[4];
  {
    const unsigned short* qrow = Qb + (size_t)(b * MK_ + q0 + w * 16 + l15) * D_ + h * HD_;
#pragma unroll
    for (int kk = 0; kk < 4; ++kk) qf[kk] = *(const short8*)(qrow + kk * 32 + g * 8);
  }

  f32x4 oacc[8] = {};
  float mrow[4], lrow[4];
#pragma unroll
  for (int r = 0; r < 4; ++r) { mrow[r] = -__builtin_inff(); lrow[r] = 0.f; }

  int qminw = q0 + w * 16;

  stage_k(Kbase, Ks, 0, w, lane);   // prologue: K(0)

  for (int t = 0; t < nt; ++t) {
    int kv0 = (t < nt - 1) ? t * 64 : MK_;

    size_t ci[4];
    float4 cv[4];
    {
      size_t i0 = cpyBase + (size_t)t * 2048 + tid;
#pragma unroll
      for (int jj = 0; jj < 4; ++jj) {
        size_t ix = i0 + jj * 512;
        ci[jj] = ix < NF4 ? ix : (NF4 - 1);
        cv[jj] = xsrc[ci[jj]];
      }
    }

    stage_v(Vbase, Vts, kv0, w, lane);
    if (t == 0) asm volatile("s_waitcnt vmcnt(6)" ::: "memory");
    else        asm volatile("s_waitcnt vmcnt(10)" ::: "memory");
    __builtin_amdgcn_s_barrier();    // barrier 1: Ks(t) visible

    bool active = (t == nt - 1) || (t * 64 <= qminw + 15);
    f32x4 sacc[4] = {};
    if (active) {
      __builtin_amdgcn_s_setprio(1);
#pragma unroll
      for (int kk = 0; kk < 4; ++kk) {
#pragma unroll
        for (int nf = 0; nf < 4; ++nf) {
          int krow = nf * 16 + l15;
          int sw = (kk * 4 + g) ^ (krow & 7);
          short8 kf = *(const short8*)(Ks + krow * 128 + sw * 8);
          sacc[nf] = __builtin_amdgcn_mfma_f32_16x16x32_bf16(qf[kk], kf, sacc[nf], 0, 0, 0);
        }
      }
      __builtin_amdgcn_s_setprio(0);
    }

    __builtin_amdgcn_s_barrier();    // barrier 1.5: all Ks reads in registers
    if (t + 1 < nt) {
      int kv1 = (t + 1 < nt - 1) ? (t + 1) * 64 : MK_;
      stage_k(Kbase, Ks, kv1, w, lane);
    }

    if (active) {
      if (t == nt - 1) {
#pragma unroll
        for (int nf = 0; nf < 4; ++nf) {
          int col = nf * 16 + l15;
          if (col != 0) {
#pragma unroll
            for (int r = 0; r < 4; ++r) sacc[nf][r] = -1e9f;
          }
        }
      } else if (t * 64 + 63 > qminw) {
        int qb = qminw - t * 64 + g * 4;
#pragma unroll
        for (int nf = 0; nf < 4; ++nf) {
          int col = nf * 16 + l15;
#pragma unroll
          for (int r = 0; r < 4; ++r)
            if (col > qb + r) sacc[nf][r] = -1e9f;
        }
      }

      float pm[4]; bool need = false;
#pragma unroll
      for (int r = 0; r < 4; ++r) {
        float mx = fmaxf(fmaxf(sacc[0][r], sacc[1][r]), fmaxf(sacc[2][r], sacc[3][r]));
        mx = fmaxf(mx, __shfl_xor(mx, 1));
        mx = fmaxf(mx, __shfl_xor(mx, 2));
        mx = fmaxf(mx, __shfl_xor(mx, 4));
        mx = fmaxf(mx, __shfl_xor(mx, 8));
        pm[r] = mx;
        need |= (mx > mrow[r] + 8.0f);
      }
      if (__any((int)need)) {
#pragma unroll
        for (int r = 0; r < 4; ++r) {
          float mnew = fmaxf(mrow[r], pm[r]);
          float sf = exp2f(mrow[r] - mnew);
          mrow[r] = mnew;
          lrow[r] *= sf;
#pragma unroll
          for (int i = 0; i < 8; ++i) oacc[i][r] *= sf;
        }
      }
      float rs[4] = {0.f, 0.f, 0.f, 0.f};
#pragma unroll
      for (int nf = 0; nf < 4; ++nf) {
#pragma unroll
        for (int r = 0; r < 4; ++r) {
          float p = exp2f(sacc[nf][r] - mrow[r]);
          sacc[nf][r] = p;
          rs[r] += p;
        }
      }
#pragma unroll
      for (int r = 0; r < 4; ++r) {
        float s = rs[r];
        s += __shfl_xor(s, 1);
        s += __shfl_xor(s, 2);
        s += __shfl_xor(s, 4);
        s += __shfl_xor(s, 8);
        lrow[r] += s;
      }
#pragma unroll
      for (int nf = 0; nf < 4; ++nf)
#pragma unroll
        for (int r = 0; r < 4; ++r)
          Ps[w][g * 4 + r][nf * 16 + l15] = f2bf(sacc[nf][r]);
    }

    if (t + 1 < nt) asm volatile("s_waitcnt vmcnt(2)" ::: "memory");
    else            asm volatile("s_waitcnt vmcnt(0)" ::: "memory");

#pragma unroll
    for (int jj = 0; jj < 4; ++jj) xdst[ci[jj]] = cv[jj];

    __builtin_amdgcn_s_barrier();    // barrier 2: Vts ready

    if (active) {
      __builtin_amdgcn_s_setprio(1);
#pragma unroll
      for (int kk = 0; kk < 2; ++kk) {
        short8 pf = *(const short8*)(&Ps[w][l15][kk * 32 + g * 8]);
#pragma unroll
        for (int nf = 0; nf < 8; ++nf) {
          int vrow = nf * 16 + l15;
          int sw = (kk * 4 + g) ^ (vrow & 7);
          short8 vf = *(const short8*)(Vts + vrow * 64 + sw * 8);
          oacc[nf] = __builtin_amdgcn_mfma_f32_16x16x32_bf16(pf, vf, oacc[nf], 0, 0, 0);
        }
      }
      __builtin_amdgcn_s_setprio(0);
    }
    __builtin_amdgcn_s_barrier();    // barrier 3: protect Vts/Ps overwrite
  }

#pragma unroll
  for (int nf = 0; nf < 8; ++nf) {
#pragma unroll
    for (int r = 0; r < 4; ++r) {
      size_t row = (size_t)b * MK_ + q0 + w * 16 + g * 4 + r;
      Ob[row * D_ + h * HD_ + nf * 16 + l15] = f2bf(oacc[nf][r] / lrow[r]);
    }
  }
}

// ------------------------------------------------------------------- launch
extern "C" void kernel_launch(void* const* d_in, const int* in_sizes, int n_in,
                              void* d_out, int out_size, void* d_ws, size_t ws_size,
                              hipStream_t stream) {
  const float* x    = (const float*)d_in[0];
  const void*  mask = d_in[1];
  const float* reg  = (const float*)d_in[2];
  const float* Wq   = (const float*)d_in[3];
  const float* bq   = (const float*)d_in[4];
  const float* Wk   = (const float*)d_in[5];
  const float* bk   = (const float*)d_in[6];
  const float* Wv   = (const float*)d_in[7];
  const float* bv   = (const float*)d_in[8];
  const float* Wrk  = (const float*)d_in[9];
  const float* brk  = (const float*)d_in[10];
  const float* Wrv  = (const float*)d_in[11];
  const float* brv  = (const float*)d_in[12];
  const float* Wo   = (const float*)d_in[13];
  const float* bo   = (const float*)d_in[14];

  char* ws = (char*)d_ws;
  int* flag            = (int*)ws;                       // 256 B
  int* rowmap          = (int*)(ws + 256);               // 32768 B
  char* p = ws + 66048;
  unsigned short* sig = (unsigned short*)p;              p += (size_t)8192 * 2048 * 2;
  unsigned short* Qb  = (unsigned short*)p;              p += (size_t)8192 * 2048 * 2;
  unsigned short* Kb  = (unsigned short*)p;              p += (size_t)8200 * 2048 * 2;
  unsigned short* Vtb = (unsigned short*)p;              p += ((size_t)16384 * VTP + 64) * 2;
  unsigned short* Wbf = (unsigned short*)p;              // 33.6 MB fused / 8.4 MB fallback
  unsigned short* Ob  = sig;  // sig dead after QKV GEMM

  const size_t need_fused = (size_t)(p - ws) + (size_t)8192 * 2048 * 2;
  const bool fused = (ws_size >= need_fused);

  detect_mask_kernel<<<1, 256, 0, stream>>>((const unsigned char*)mask, flag);
  build_rowmap_kernel<<<8, 256, 0, stream>>>(mask, flag, rowmap);
  gather_sig_kernel<<<8192, 256, 0, stream>>>(x, rowmap, sig);
  reg_kv_kernel<<<1024, 256, 0, stream>>>(reg, Wrk, brk, Wrv, brv, Kb, Vtb);

  const float qalpha = 0.08838834764831845f * 1.4426950408889634f;
  const size_t per = (size_t)2048 * 2048;

  if (fused) {
    conv_bf16_kernel<<<8192, 256, 0, stream>>>(Wq, Wk, Wv, Wo, Wbf);
    gemm8_kernel<1><<<768, 512, 0, stream>>>(sig, Wbf, bq, bk, bv, Qb, Kb, Vtb,
                                             nullptr, qalpha, 24, -1);
    attn_kernel<<<1024, 512, 0, stream>>>(Qb, Kb, Vtb, Ob, (const float4*)x, (float4*)d_out);
    gemm8_kernel<0><<<256, 512, 0, stream>>>(Ob, Wbf + 3 * per, bo, nullptr, nullptr,
                                             d_out, nullptr, nullptr, rowmap, 1.0f, 8, -1);
  } else {
    conv_bf16_kernel<<<2048, 256, 0, stream>>>(Wq, Wq, Wq, Wq, Wbf);
    gemm8_kernel<1><<<256, 512, 0, stream>>>(sig, Wbf, bq, bk, bv, Qb, Kb, Vtb,
                                             nullptr, qalpha, 8, 0);
    conv_bf16_kernel<<<2048, 256, 0, stream>>>(Wk, Wk, Wk, Wk, Wbf);
    gemm8_kernel<1><<<256, 512, 0, stream>>>(sig, Wbf, bq, bk, bv, Qb, Kb, Vtb,
                                             nullptr, qalpha, 8, 1);
    conv_bf16_kernel<<<2048, 256, 0, stream>>>(Wv, Wv, Wv, Wv, Wbf);
    gemm8_kernel<1><<<256, 512, 0, stream>>>(sig, Wbf, bq, bk, bv, Qb, Kb, Vtb,
                                             nullptr, qalpha, 8, 2);
    attn_kernel<<<1024, 512, 0, stream>>>(Qb, Kb, Vtb, Ob, (const float4*)x, (float4*)d_out);
    conv_bf16_kernel<<<2048, 256, 0, stream>>>(Wo, Wo, Wo, Wo, Wbf);
    gemm8_kernel<0><<<256, 512, 0, stream>>>(Ob, Wbf, bo, nullptr, nullptr,
                                             d_out, nullptr, nullptr, rowmap, 1.0f, 8, -1);
  }
}

// Round 11
// 513.379 us; speedup vs baseline: 1.0372x; 1.0362x over previous
//
#include <hip/hip_runtime.h>
#include <hip/hip_bf16.h>

#define B_  8
#define L_  4096
#define D_  2048
#define H_  16
#define HD_ 128
#define MK_ 1024
#define VTP 1040   // Vt row pitch (k dim, 1025 used + pad)

typedef __attribute__((ext_vector_type(8))) short short8;
typedef __attribute__((ext_vector_type(4))) float f32x4;

__device__ inline unsigned short f2bf(float f) {
  unsigned int u = __float_as_uint(f);
  unsigned int r = (u + 0x7fffu + ((u >> 16) & 1u)) >> 16;   // RNE
  return (unsigned short)r;
}

__device__ __forceinline__ void gload_lds16(const void* g, void* l) {
  __builtin_amdgcn_global_load_lds(
      (const __attribute__((address_space(1))) void*)g,
      (__attribute__((address_space(3))) void*)l, 16, 0, 0);
}

// ---------------- prep1: mask-dtype detect + rowmap (blocks 0..7) + weight conv
// conv blocks convert nconv slabs of D*D f32 -> bf16 into Wb.
__global__ __launch_bounds__(256) void prep1_kernel(
    const void* __restrict__ maskv, int* __restrict__ rowmap,
    const float* __restrict__ W0, const float* __restrict__ W1,
    const float* __restrict__ W2, const float* __restrict__ W3,
    unsigned short* __restrict__ Wb) {
  int bid = blockIdx.x;
  int tid = threadIdx.x;
  if (bid < 8) {
    // local dtype detect (count nonzero bytes in first 32768 bytes)
    __shared__ int cnt;
    __shared__ int cnts[256];
    const unsigned char* m8 = (const unsigned char*)maskv;
    if (tid == 0) cnt = 0;
    __syncthreads();
    int local = 0;
    for (int i = tid; i < B_ * L_; i += 256) local += (m8[i] != 0);
    atomicAdd(&cnt, local);
    __syncthreads();
    int cv = cnt;
    int t = 0;
    if (cv == B_ * MK_)      t = 0; // u8 bool
    else if (cv == 2 * MK_)  t = 1; // i32
    else if (cv == 4 * MK_)  t = 2; // f32
    // compaction for batch b = bid
    int b = bid;
    unsigned char loc[16];
    int c = 0;
    for (int j = 0; j < 16; ++j) {
      int pos = tid * 16 + j;
      int mv;
      if (t == 1)      mv = ((const int*)maskv)[b * L_ + pos] != 0;
      else if (t == 2) mv = ((const float*)maskv)[b * L_ + pos] != 0.0f;
      else             mv = m8[b * L_ + pos] != 0;
      loc[j] = (unsigned char)mv; c += mv;
    }
    cnts[tid] = c;
    __syncthreads();
    for (int off = 1; off < 256; off <<= 1) {
      int v = (tid >= off) ? cnts[tid - off] : 0;
      __syncthreads();
      cnts[tid] += v;
      __syncthreads();
    }
    int rank = cnts[tid] - c;
    for (int j = 0; j < 16; ++j) {
      if (loc[j]) {
        if (rank < MK_) rowmap[b * MK_ + rank] = b * L_ + tid * 16 + j;
        ++rank;
      }
    }
  } else {
    const size_t per = (size_t)D_ * D_;
    int cb = bid - 8;
    int slab = cb >> 11;
    const float* W = (slab == 0) ? W0 : (slab == 1) ? W1 : (slab == 2) ? W2 : W3;
    size_t i = ((size_t)(cb & 2047) * 256 + tid) * 8;
    float4 a = *(const float4*)(W + i);
    float4 b4 = *(const float4*)(W + i + 4);
    uint4 o;
    o.x = f2bf(a.x)  | ((unsigned)f2bf(a.y)  << 16);
    o.y = f2bf(a.z)  | ((unsigned)f2bf(a.w)  << 16);
    o.z = f2bf(b4.x) | ((unsigned)f2bf(b4.y) << 16);
    o.w = f2bf(b4.z) | ((unsigned)f2bf(b4.w) << 16);
    *(uint4*)(Wb + slab * per + i) = o;
  }
}

// ---------------- prep2: gather+convert sig (blocks 0..8191) + register K/V rows
__global__ __launch_bounds__(256) void prep2_kernel(
    const float* __restrict__ x, const int* __restrict__ rowmap,
    unsigned short* __restrict__ sig,
    const float* __restrict__ reg, const float* __restrict__ Wrk, const float* __restrict__ brk,
    const float* __restrict__ Wrv, const float* __restrict__ brv,
    unsigned short* __restrict__ Kb, unsigned short* __restrict__ Vt) {
  int bid = blockIdx.x;
  int tid = threadIdx.x;
  if (bid < 8192) {
    int row = bid;
    const float* src = x + (size_t)rowmap[row] * D_;
    unsigned short* dst = sig + (size_t)row * D_;
    float4 a = ((const float4*)src)[tid * 2];
    float4 b4 = ((const float4*)src)[tid * 2 + 1];
    uint4 o;
    o.x = f2bf(a.x)  | ((unsigned)f2bf(a.y)  << 16);
    o.y = f2bf(a.z)  | ((unsigned)f2bf(a.w)  << 16);
    o.z = f2bf(b4.x) | ((unsigned)f2bf(b4.y) << 16);
    o.w = f2bf(b4.z) | ((unsigned)f2bf(b4.w) << 16);
    *(uint4*)(dst + tid * 8) = o;
  } else {
    int gw = ((bid - 8192) * 256 + tid) >> 6;  // 4096 waves
    int lane = tid & 63;
    int mat = gw >> 11;
    int n = gw & 2047;
    const float* W = mat ? Wrv : Wrk;
    const float* wrow = W + (size_t)n * D_;
    float s[8] = {};
    for (int j = 0; j < 8; ++j) {
      int e = j * 256 + lane * 4;
      float4 wv = *(const float4*)(wrow + e);
#pragma unroll
      for (int b = 0; b < 8; ++b) {
        float4 rv = *(const float4*)(reg + (size_t)b * D_ + e);
        s[b] += wv.x * rv.x + wv.y * rv.y + wv.z * rv.z + wv.w * rv.w;
      }
    }
#pragma unroll
    for (int off = 32; off; off >>= 1)
#pragma unroll
      for (int b = 0; b < 8; ++b) s[b] += __shfl_down(s[b], off);
    if (lane == 0) {
      float bias = (mat ? brv : brk)[n];
#pragma unroll
      for (int b = 0; b < 8; ++b) {
        unsigned short v = f2bf(s[b] + bias);
        if (mat) {
          Vt[(((size_t)b * 16 + (n >> 7)) * 128 + (n & 127)) * VTP + 1024] = v;
        } else {
          Kb[((size_t)b * 1025 + 1024) * D_ + n] = v;
        }
      }
    }
  }
}

// ------------------------------------------------- 256x256 BK=64 pipelined GEMM
// 2 LDS buffers, 4 MFMA clusters of 16 per K-tile, ONE barrier + ONE vmcnt(0)
// per K-tile. Both A and B stages for kt+1 issued at cluster 0 -> each load has
// a full tile (~1250 cyc) of lead before the end-of-tile drain (>= HBM ~900).
template<int FUSED>
__global__ __launch_bounds__(512, 2) void gemm8_kernel(
    const unsigned short* __restrict__ A, const unsigned short* __restrict__ Bw,
    const float* __restrict__ b0, const float* __restrict__ b1, const float* __restrict__ b2,
    void* __restrict__ O0, void* __restrict__ O1, void* __restrict__ O2,
    const int* __restrict__ rowmap, float qalpha, int nbt, int matfix) {
  __shared__ __align__(16) unsigned short lds[2][2][16384];  // [buf][A/B][256 rows x 64 k]
  int tid = threadIdx.x, lane = tid & 63, w = tid >> 6;
  int g = lane >> 4, l15 = lane & 15;
  int wm = w >> 2, wn = w & 3;

  int bid = blockIdx.x;
  int xcd = bid & 7, j = bid >> 3;          // grid = 8 * (4 * nbt)
  int mb = xcd * 4 + j / nbt, nb = j % nbt;
  int m0 = mb * 256, n0 = nb * 256;

  f32x4 acc[2][4][4] = {};

  size_t aoff[4], boff[4];
  int ldsoff[4];
#pragma unroll
  for (int i = 0; i < 4; ++i) {
    int chunk = tid + i * 512;
    int row = chunk >> 3;
    int gslot = (chunk & 7) ^ (row & 7);
    aoff[i] = (size_t)(m0 + row) * D_ + gslot * 8;
    boff[i] = (size_t)(n0 + row) * D_ + gslot * 8;
    ldsoff[i] = (w * 64 + i * 512) * 8;
  }

#define STAGE_A(kt, BUF) {                                              \
    _Pragma("unroll")                                                   \
    for (int i_ = 0; i_ < 4; ++i_)                                      \
      gload_lds16(A + aoff[i_] + (kt) * 64, &lds[BUF][0][ldsoff[i_]]);  \
  }
#define STAGE_B(kt, BUF) {                                              \
    _Pragma("unroll")                                                   \
    for (int i_ = 0; i_ < 4; ++i_)                                      \
      gload_lds16(Bw + boff[i_] + (kt) * 64, &lds[BUF][1][ldsoff[i_]]); \
  }
#define RD_A(dst, BUF, h, kk) {                                         \
    _Pragma("unroll")                                                   \
    for (int mf_ = 0; mf_ < 4; ++mf_) {                                 \
      int r_ = wm * 128 + (h) * 64 + mf_ * 16 + l15;                    \
      dst[mf_] = *(const short8*)(&lds[BUF][0][r_ * 64 + (((kk) * 4 + g) ^ (r_ & 7)) * 8]); } \
  }
#define RD_B(dst, BUF, kk) {                                            \
    _Pragma("unroll")                                                   \
    for (int nf_ = 0; nf_ < 4; ++nf_) {                                 \
      int r_ = wn * 64 + nf_ * 16 + l15;                                \
      dst[nf_] = *(const short8*)(&lds[BUF][1][r_ * 64 + (((kk) * 4 + g) ^ (r_ & 7)) * 8]); } \
  }
#define MFMA16(h, af, bf) {                                             \
    _Pragma("unroll")                                                   \
    for (int mf_ = 0; mf_ < 4; ++mf_)                                   \
      _Pragma("unroll")                                                 \
      for (int nf_ = 0; nf_ < 4; ++nf_)                                 \
        acc[h][mf_][nf_] = __builtin_amdgcn_mfma_f32_16x16x32_bf16(af[mf_], bf[nf_], acc[h][mf_][nf_], 0, 0, 0); \
  }

  // prologue: stage tile 0, drain, barrier
  STAGE_A(0, 0); STAGE_B(0, 0);
  asm volatile("s_waitcnt vmcnt(0)" ::: "memory");
  __builtin_amdgcn_s_barrier();

  short8 afE[4], afO[4], bf0[4], bf1[4];

#define KTILE(kt, BUF)                                                    \
  {                                                                       \
    RD_B(bf0, BUF, 0); RD_B(bf1, BUF, 1); RD_A(afE, BUF, 0, 0);           \
    /* c0: half0/kk0 — both next-tile stages issued here (full-tile lead) */ \
    RD_A(afO, BUF, 0, 1);                                                 \
    if ((kt) + 1 < 32) { STAGE_A((kt) + 1, BUF ^ 1); STAGE_B((kt) + 1, BUF ^ 1); } \
    asm volatile("s_waitcnt lgkmcnt(4)" ::: "memory");                    \
    __builtin_amdgcn_sched_barrier(0);                                    \
    __builtin_amdgcn_s_setprio(1);                                        \
    MFMA16(0, afE, bf0);                                                  \
    __builtin_amdgcn_s_setprio(0);                                        \
    /* c1: half0/kk1 */                                                   \
    RD_A(afE, BUF, 1, 0);                                                 \
    asm volatile("s_waitcnt lgkmcnt(4)" ::: "memory");                    \
    __builtin_amdgcn_sched_barrier(0);                                    \
    __builtin_amdgcn_s_setprio(1);                                        \
    MFMA16(0, afO, bf1);                                                  \
    __builtin_amdgcn_s_setprio(0);                                        \
    /* c2: half1/kk0 */                                                   \
    RD_A(afO, BUF, 1, 1);                                                 \
    asm volatile("s_waitcnt lgkmcnt(4)" ::: "memory");                    \
    __builtin_amdgcn_sched_barrier(0);                                    \
    __builtin_amdgcn_s_setprio(1);                                        \
    MFMA16(1, afE, bf0);                                                  \
    __builtin_amdgcn_s_setprio(0);                                        \
    /* c3: half1/kk1 */                                                   \
    asm volatile("s_waitcnt lgkmcnt(0)" ::: "memory");                    \
    __builtin_amdgcn_sched_barrier(0);                                    \
    __builtin_amdgcn_s_setprio(1);                                        \
    MFMA16(1, afO, bf1);                                                  \
    __builtin_amdgcn_s_setprio(0);                                        \
    asm volatile("s_waitcnt vmcnt(0)" ::: "memory");                      \
    __builtin_amdgcn_s_barrier();                                         \
  }

  for (int kt2 = 0; kt2 < 16; ++kt2) {
    KTILE(2 * kt2,     0);
    KTILE(2 * kt2 + 1, 1);
  }
#undef KTILE
#undef MFMA16
#undef RD_A
#undef RD_B
#undef STAGE_A
#undef STAGE_B

  int mat = 0;
  const float* bias = b0;
  float alpha = 1.0f;
  int n0l = n0;
  if (FUSED) {
    mat = (matfix >= 0) ? matfix : (n0 >> 11);
    bias = (mat == 0) ? b0 : ((mat == 1) ? b1 : b2);
    alpha = (mat == 0) ? qalpha : 1.0f;
    n0l = n0 & 2047;
  }

#pragma unroll
  for (int ph = 0; ph < 2; ++ph) {
#pragma unroll
    for (int mf = 0; mf < 4; ++mf) {
#pragma unroll
      for (int nf = 0; nf < 4; ++nf) {
        int nn = n0l + wn * 64 + nf * 16 + l15;
        float bvv = bias[nn];
        int m = m0 + wm * 128 + ph * 64 + mf * 16 + g * 4;
        if (FUSED) {
          if (mat == 2) {                      // V -> transposed Vt
            int bb = m >> 10, tok = m & 1023;
            size_t base = (((size_t)bb * 16 + (nn >> 7)) * 128 + (nn & 127)) * VTP + tok;
            uint2 u;
            u.x = f2bf(acc[ph][mf][nf][0] + bvv) | ((unsigned)f2bf(acc[ph][mf][nf][1] + bvv) << 16);
            u.y = f2bf(acc[ph][mf][nf][2] + bvv) | ((unsigned)f2bf(acc[ph][mf][nf][3] + bvv) << 16);
            *(uint2*)((unsigned short*)O2 + base) = u;
          } else {
            unsigned short* out = (mat == 0) ? (unsigned short*)O0 : (unsigned short*)O1;
#pragma unroll
            for (int r = 0; r < 4; ++r) {
              float v = (acc[ph][mf][nf][r] + bvv) * alpha;
              int mm = m + r;
              int row = (mat == 1) ? mm + (mm >> 10) : mm;
              out[(size_t)row * D_ + nn] = f2bf(v);
            }
          }
        } else {
#pragma unroll
          for (int r = 0; r < 4; ++r) {
            int row = rowmap[m + r];
            ((float*)O0)[(size_t)row * D_ + nn] = acc[ph][mf][nf][r] + bvv;
          }
        }
      }
    }
  }
}

// ----------------------------------------------------------- flash attention
// (unchanged — single-buffer K, early prefetch, fused x->out copy)
__device__ __forceinline__ void stage_k(const unsigned short* Kbase, unsigned short* dst,
                                        int kv0, int w, int lane) {
#pragma unroll
  for (int i = 0; i < 2; ++i) {
    int ib = w * 2 + i;
    int row = ib * 4 + (lane >> 4);
    int sl = (lane & 15) ^ (row & 7);
    int krow = kv0 + row; if (krow > MK_) krow = MK_;
    gload_lds16(Kbase + (size_t)krow * D_ + sl * 8, dst + ib * 512);
  }
}
__device__ __forceinline__ void stage_v(const unsigned short* Vbase, unsigned short* dst,
                                        int kv0, int w, int lane) {
#pragma unroll
  for (int i = 0; i < 2; ++i) {
    int ib = w * 2 + i;
    int row = ib * 8 + (lane >> 3);
    int sl = (lane & 7) ^ (row & 7);
    gload_lds16(Vbase + (size_t)row * VTP + kv0 + sl * 8, dst + ib * 512);
  }
}

#define NF4 16777216   // total float4 in x (8*4096*2048/4)

__global__ __launch_bounds__(512) void attn_kernel(
    const unsigned short* __restrict__ Qb, const unsigned short* __restrict__ Kb,
    const unsigned short* __restrict__ Vt, unsigned short* __restrict__ Ob,
    const float4* __restrict__ xsrc, float4* __restrict__ xdst) {
  int bx = blockIdx.x;
  int gq = bx >> 7;                // 0 = heaviest
  int qi = 7 - gq;
  int bh = bx & 127;
  int b = bh >> 4, h = bh & 15;
  int tid = threadIdx.x, lane = tid & 63, w = tid >> 6;
  int g = lane >> 4, l15 = lane & 15;
  int q0 = qi * 128;
  int nt = 2 * qi + 3;             // causal tiles + register tile

  size_t cpyBase = ((size_t)128 * (18 * gq - gq * gq) + (size_t)(bx & 127) * nt) * 2048;

  __shared__ __align__(16) unsigned short Ks[64 * 128];   // 16 KB, single buffer
  __shared__ __align__(16) unsigned short Vts[128 * 64];  // 16 KB
  __shared__ __align__(16) unsigned short Ps[8][16][72];  // 18 KB

  const unsigned short* Kbase = Kb + (size_t)b * 1025 * D_ + h * HD_;
  const unsigned short* Vbase = Vt + (size_t)bh * 128 * VTP;

  short8 qf[4];
  {
    const unsigned short* qrow = Qb + (size_t)(b * MK_ + q0 + w * 16 + l15) * D_ + h * HD_;
#pragma unroll
    for (int kk = 0; kk < 4; ++kk) qf[kk] = *(const short8*)(qrow + kk * 32 + g * 8);
  }

  f32x4 oacc[8] = {};
  float mrow[4], lrow[4];
#pragma unroll
  for (int r = 0; r < 4; ++r) { mrow[r] = -__builtin_inff(); lrow[r] = 0.f; }

  int qminw = q0 + w * 16;

  stage_k(Kbase, Ks, 0, w, lane);   // prologue: K(0)

  for (int t = 0; t < nt; ++t) {
    int kv0 = (t < nt - 1) ? t * 64 : MK_;

    size_t ci[4];
    float4 cv[4];
    {
      size_t i0 = cpyBase + (size_t)t * 2048 + tid;
#pragma unroll
      for (int jj = 0; jj < 4; ++jj) {
        size_t ix = i0 + jj * 512;
        ci[jj] = ix < NF4 ? ix : (NF4 - 1);
        cv[jj] = xsrc[ci[jj]];
      }
    }

    stage_v(Vbase, Vts, kv0, w, lane);
    if (t == 0) asm volatile("s_waitcnt vmcnt(6)" ::: "memory");
    else        asm volatile("s_waitcnt vmcnt(10)" ::: "memory");
    __builtin_amdgcn_s_barrier();    // barrier 1: Ks(t) visible

    bool active = (t == nt - 1) || (t * 64 <= qminw + 15);
    f32x4 sacc[4] = {};
    if (active) {
      __builtin_amdgcn_s_setprio(1);
#pragma unroll
      for (int kk = 0; kk < 4; ++kk) {
#pragma unroll
        for (int nf = 0; nf < 4; ++nf) {
          int krow = nf * 16 + l15;
          int sw = (kk * 4 + g) ^ (krow & 7);
          short8 kf = *(const short8*)(Ks + krow * 128 + sw * 8);
          sacc[nf] = __builtin_amdgcn_mfma_f32_16x16x32_bf16(qf[kk], kf, sacc[nf], 0, 0, 0);
        }
      }
      __builtin_amdgcn_s_setprio(0);
    }

    __builtin_amdgcn_s_barrier();    // barrier 1.5: all Ks reads in registers
    if (t + 1 < nt) {
      int kv1 = (t + 1 < nt - 1) ? (t + 1) * 64 : MK_;
      stage_k(Kbase, Ks, kv1, w, lane);
    }

    if (active) {
      if (t == nt - 1) {
#pragma unroll
        for (int nf = 0; nf < 4; ++nf) {
          int col = nf * 16 + l15;
          if (col != 0) {
#pragma unroll
            for (int r = 0; r < 4; ++r) sacc[nf][r] = -1e9f;
          }
        }
      } else if (t * 64 + 63 > qminw) {
        int qb = qminw - t * 64 + g * 4;
#pragma unroll
        for (int nf = 0; nf < 4; ++nf) {
          int col = nf * 16 + l15;
#pragma unroll
          for (int r = 0; r < 4; ++r)
            if (col > qb + r) sacc[nf][r] = -1e9f;
        }
      }

      float pm[4]; bool need = false;
#pragma unroll
      for (int r = 0; r < 4; ++r) {
        float mx = fmaxf(fmaxf(sacc[0][r], sacc[1][r]), fmaxf(sacc[2][r], sacc[3][r]));
        mx = fmaxf(mx, __shfl_xor(mx, 1));
        mx = fmaxf(mx, __shfl_xor(mx, 2));
        mx = fmaxf(mx, __shfl_xor(mx, 4));
        mx = fmaxf(mx, __shfl_xor(mx, 8));
        pm[r] = mx;
        need |= (mx > mrow[r] + 8.0f);
      }
      if (__any((int)need)) {
#pragma unroll
        for (int r = 0; r < 4; ++r) {
          float mnew = fmaxf(mrow[r], pm[r]);
          float sf = exp2f(mrow[r] - mnew);
          mrow[r] = mnew;
          lrow[r] *= sf;
#pragma unroll
          for (int i = 0; i < 8; ++i) oacc[i][r] *= sf;
        }
      }
      float rs[4] = {0.f, 0.f, 0.f, 0.f};
#pragma unroll
      for (int nf = 0; nf < 4; ++nf) {
#pragma unroll
        for (int r = 0; r < 4; ++r) {
          float p = exp2f(sacc[nf][r] - mrow[r]);
          sacc[nf][r] = p;
          rs[r] += p;
        }
      }
#pragma unroll
      for (int r = 0; r < 4; ++r) {
        float s = rs[r];
        s += __shfl_xor(s, 1);
        s += __shfl_xor(s, 2);
        s += __shfl_xor(s, 4);
        s += __shfl_xor(s, 8);
        lrow[r] += s;
      }
#pragma unroll
      for (int nf = 0; nf < 4; ++nf)
#pragma unroll
        for (int r = 0; r < 4; ++r)
          Ps[w][g * 4 + r][nf * 16 + l15] = f2bf(sacc[nf][r]);
    }

    if (t + 1 < nt) asm volatile("s_waitcnt vmcnt(2)" ::: "memory");
    else            asm volatile("s_waitcnt vmcnt(0)" ::: "memory");

#pragma unroll
    for (int jj = 0; jj < 4; ++jj) xdst[ci[jj]] = cv[jj];

    __builtin_amdgcn_s_barrier();    // barrier 2: Vts ready

    if (active) {
      __builtin_amdgcn_s_setprio(1);
#pragma unroll
      for (int kk = 0; kk < 2; ++kk) {
        short8 pf = *(const short8*)(&Ps[w][l15][kk * 32 + g * 8]);
#pragma unroll
        for (int nf = 0; nf < 8; ++nf) {
          int vrow = nf * 16 + l15;
          int sw = (kk * 4 + g) ^ (vrow & 7);
          short8 vf = *(const short8*)(Vts + vrow * 64 + sw * 8);
          oacc[nf] = __builtin_amdgcn_mfma_f32_16x16x32_bf16(pf, vf, oacc[nf], 0, 0, 0);
        }
      }
      __builtin_amdgcn_s_setprio(0);
    }
    __builtin_amdgcn_s_barrier();    // barrier 3: protect Vts/Ps overwrite
  }

#pragma unroll
  for (int nf = 0; nf < 8; ++nf) {
#pragma unroll
    for (int r = 0; r < 4; ++r) {
      size_t row = (size_t)b * MK_ + q0 + w * 16 + g * 4 + r;
      Ob[row * D_ + h * HD_ + nf * 16 + l15] = f2bf(oacc[nf][r] / lrow[r]);
    }
  }
}

// ------------------------------------------------------------------- launch
extern "C" void kernel_launch(void* const* d_in, const int* in_sizes, int n_in,
                              void* d_out, int out_size, void* d_ws, size_t ws_size,
                              hipStream_t stream) {
  const float* x    = (const float*)d_in[0];
  const void*  mask = d_in[1];
  const float* reg  = (const float*)d_in[2];
  const float* Wq   = (const float*)d_in[3];
  const float* bq   = (const float*)d_in[4];
  const float* Wk   = (const float*)d_in[5];
  const float* bk   = (const float*)d_in[6];
  const float* Wv   = (const float*)d_in[7];
  const float* bv   = (const float*)d_in[8];
  const float* Wrk  = (const float*)d_in[9];
  const float* brk  = (const float*)d_in[10];
  const float* Wrv  = (const float*)d_in[11];
  const float* brv  = (const float*)d_in[12];
  const float* Wo   = (const float*)d_in[13];
  const float* bo   = (const float*)d_in[14];

  char* ws = (char*)d_ws;
  int* rowmap          = (int*)(ws + 256);               // 32768 B
  char* p = ws + 66048;
  unsigned short* sig = (unsigned short*)p;              p += (size_t)8192 * 2048 * 2;
  unsigned short* Qb  = (unsigned short*)p;              p += (size_t)8192 * 2048 * 2;
  unsigned short* Kb  = (unsigned short*)p;              p += (size_t)8200 * 2048 * 2;
  unsigned short* Vtb = (unsigned short*)p;              p += ((size_t)16384 * VTP + 64) * 2;
  unsigned short* Wbf = (unsigned short*)p;              // 33.6 MB fused / 8.4 MB fallback
  unsigned short* Ob  = sig;  // sig dead after QKV GEMM

  const size_t need_fused = (size_t)(p - ws) + (size_t)8192 * 2048 * 2;
  const bool fused = (ws_size >= need_fused);

  const float qalpha = 0.08838834764831845f * 1.4426950408889634f;
  const size_t per = (size_t)2048 * 2048;

  if (fused) {
    // prep1: rowmap (8 blocks) + all 4 weight-conversions (8192 blocks)
    prep1_kernel<<<8200, 256, 0, stream>>>(mask, rowmap, Wq, Wk, Wv, Wo, Wbf);
    // prep2: gather sig (8192 blocks) + register K/V rows (1024 blocks)
    prep2_kernel<<<9216, 256, 0, stream>>>(x, rowmap, sig, reg, Wrk, brk, Wrv, brv, Kb, Vtb);
    gemm8_kernel<1><<<768, 512, 0, stream>>>(sig, Wbf, bq, bk, bv, Qb, Kb, Vtb,
                                             nullptr, qalpha, 24, -1);
    attn_kernel<<<1024, 512, 0, stream>>>(Qb, Kb, Vtb, Ob, (const float4*)x, (float4*)d_out);
    gemm8_kernel<0><<<256, 512, 0, stream>>>(Ob, Wbf + 3 * per, bo, nullptr, nullptr,
                                             d_out, nullptr, nullptr, rowmap, 1.0f, 8, -1);
  } else {
    // fallback: small ws — rowmap only in prep1, weights converted one at a time
    prep1_kernel<<<8, 256, 0, stream>>>(mask, rowmap, Wq, Wk, Wv, Wo, Wbf);
    prep2_kernel<<<9216, 256, 0, stream>>>(x, rowmap, sig, reg, Wrk, brk, Wrv, brv, Kb, Vtb);
    prep1_kernel<<<8200, 256, 0, stream>>>(mask, rowmap, Wq, Wq, Wq, Wq, Wbf);  // slab0 = Wq (others overwrite same ws? no: 4 slabs of Wq — only slab 0 used)
    gemm8_kernel<1><<<256, 512, 0, stream>>>(sig, Wbf, bq, bk, bv, Qb, Kb, Vtb,
                                             nullptr, qalpha, 8, 0);
    prep1_kernel<<<8200, 256, 0, stream>>>(mask, rowmap, Wk, Wk, Wk, Wk, Wbf);
    gemm8_kernel<1><<<256, 512, 0, stream>>>(sig, Wbf, bq, bk, bv, Qb, Kb, Vtb,
                                             nullptr, qalpha, 8, 1);
    prep1_kernel<<<8200, 256, 0, stream>>>(mask, rowmap, Wv, Wv, Wv, Wv, Wbf);
    gemm8_kernel<1><<<256, 512, 0, stream>>>(sig, Wbf, bq, bk, bv, Qb, Kb, Vtb,
                                             nullptr, qalpha, 8, 2);
    attn_kernel<<<1024, 512, 0, stream>>>(Qb, Kb, Vtb, Ob, (const float4*)x, (float4*)d_out);
    prep1_kernel<<<8200, 256, 0, stream>>>(mask, rowmap, Wo, Wo, Wo, Wo, Wbf);
    gemm8_kernel<0><<<256, 512, 0, stream>>>(Ob, Wbf, bo, nullptr, nullptr,
                                             d_out, nullptr, nullptr, rowmap, 1.0f, 8, -1);
  }
}

// Round 12
// 503.186 us; speedup vs baseline: 1.0582x; 1.0203x over previous
//
#include <hip/hip_runtime.h>
#include <hip/hip_bf16.h>

#define B_  8
#define L_  4096
#define D_  2048
#define H_  16
#define HD_ 128
#define MK_ 1024
#define VTP 1040   // Vt row pitch (k dim, 1025 used + pad)

typedef __attribute__((ext_vector_type(8))) short short8;
typedef __attribute__((ext_vector_type(4))) float f32x4;

__device__ inline unsigned short f2bf(float f) {
  unsigned int u = __float_as_uint(f);
  unsigned int r = (u + 0x7fffu + ((u >> 16) & 1u)) >> 16;   // RNE
  return (unsigned short)r;
}

__device__ __forceinline__ void gload_lds16(const void* g, void* l) {
  __builtin_amdgcn_global_load_lds(
      (const __attribute__((address_space(1))) void*)g,
      (__attribute__((address_space(3))) void*)l, 16, 0, 0);
}

// ---------------- prep1: mask-dtype detect + rowmap (blocks 0..7) + weight conv
__global__ __launch_bounds__(256) void prep1_kernel(
    const void* __restrict__ maskv, int* __restrict__ rowmap,
    const float* __restrict__ W0, const float* __restrict__ W1,
    const float* __restrict__ W2, const float* __restrict__ W3,
    unsigned short* __restrict__ Wb) {
  int bid = blockIdx.x;
  int tid = threadIdx.x;
  if (bid < 8) {
    __shared__ int cnt;
    __shared__ int cnts[256];
    const unsigned char* m8 = (const unsigned char*)maskv;
    if (tid == 0) cnt = 0;
    __syncthreads();
    int local = 0;
    for (int i = tid; i < B_ * L_; i += 256) local += (m8[i] != 0);
    atomicAdd(&cnt, local);
    __syncthreads();
    int cv = cnt;
    int t = 0;
    if (cv == B_ * MK_)      t = 0; // u8 bool
    else if (cv == 2 * MK_)  t = 1; // i32
    else if (cv == 4 * MK_)  t = 2; // f32
    int b = bid;
    unsigned char loc[16];
    int c = 0;
    for (int j = 0; j < 16; ++j) {
      int pos = tid * 16 + j;
      int mv;
      if (t == 1)      mv = ((const int*)maskv)[b * L_ + pos] != 0;
      else if (t == 2) mv = ((const float*)maskv)[b * L_ + pos] != 0.0f;
      else             mv = m8[b * L_ + pos] != 0;
      loc[j] = (unsigned char)mv; c += mv;
    }
    cnts[tid] = c;
    __syncthreads();
    for (int off = 1; off < 256; off <<= 1) {
      int v = (tid >= off) ? cnts[tid - off] : 0;
      __syncthreads();
      cnts[tid] += v;
      __syncthreads();
    }
    int rank = cnts[tid] - c;
    for (int j = 0; j < 16; ++j) {
      if (loc[j]) {
        if (rank < MK_) rowmap[b * MK_ + rank] = b * L_ + tid * 16 + j;
        ++rank;
      }
    }
  } else {
    const size_t per = (size_t)D_ * D_;
    int cb = bid - 8;
    int slab = cb >> 11;
    const float* W = (slab == 0) ? W0 : (slab == 1) ? W1 : (slab == 2) ? W2 : W3;
    size_t i = ((size_t)(cb & 2047) * 256 + tid) * 8;
    float4 a = *(const float4*)(W + i);
    float4 b4 = *(const float4*)(W + i + 4);
    uint4 o;
    o.x = f2bf(a.x)  | ((unsigned)f2bf(a.y)  << 16);
    o.y = f2bf(a.z)  | ((unsigned)f2bf(a.w)  << 16);
    o.z = f2bf(b4.x) | ((unsigned)f2bf(b4.y) << 16);
    o.w = f2bf(b4.z) | ((unsigned)f2bf(b4.w) << 16);
    *(uint4*)(Wb + slab * per + i) = o;
  }
}

// ---------------- prep2: gather+convert sig (blocks 0..8191) + register K/V rows
__global__ __launch_bounds__(256) void prep2_kernel(
    const float* __restrict__ x, const int* __restrict__ rowmap,
    unsigned short* __restrict__ sig,
    const float* __restrict__ reg, const float* __restrict__ Wrk, const float* __restrict__ brk,
    const float* __restrict__ Wrv, const float* __restrict__ brv,
    unsigned short* __restrict__ Kb, unsigned short* __restrict__ Vt) {
  int bid = blockIdx.x;
  int tid = threadIdx.x;
  if (bid < 8192) {
    int row = bid;
    const float* src = x + (size_t)rowmap[row] * D_;
    unsigned short* dst = sig + (size_t)row * D_;
    float4 a = ((const float4*)src)[tid * 2];
    float4 b4 = ((const float4*)src)[tid * 2 + 1];
    uint4 o;
    o.x = f2bf(a.x)  | ((unsigned)f2bf(a.y)  << 16);
    o.y = f2bf(a.z)  | ((unsigned)f2bf(a.w)  << 16);
    o.z = f2bf(b4.x) | ((unsigned)f2bf(b4.y) << 16);
    o.w = f2bf(b4.z) | ((unsigned)f2bf(b4.w) << 16);
    *(uint4*)(dst + tid * 8) = o;
  } else {
    int gw = ((bid - 8192) * 256 + tid) >> 6;  // 4096 waves
    int lane = tid & 63;
    int mat = gw >> 11;
    int n = gw & 2047;
    const float* W = mat ? Wrv : Wrk;
    const float* wrow = W + (size_t)n * D_;
    float s[8] = {};
    for (int j = 0; j < 8; ++j) {
      int e = j * 256 + lane * 4;
      float4 wv = *(const float4*)(wrow + e);
#pragma unroll
      for (int b = 0; b < 8; ++b) {
        float4 rv = *(const float4*)(reg + (size_t)b * D_ + e);
        s[b] += wv.x * rv.x + wv.y * rv.y + wv.z * rv.z + wv.w * rv.w;
      }
    }
#pragma unroll
    for (int off = 32; off; off >>= 1)
#pragma unroll
      for (int b = 0; b < 8; ++b) s[b] += __shfl_down(s[b], off);
    if (lane == 0) {
      float bias = (mat ? brv : brk)[n];
#pragma unroll
      for (int b = 0; b < 8; ++b) {
        unsigned short v = f2bf(s[b] + bias);
        if (mat) {
          Vt[(((size_t)b * 16 + (n >> 7)) * 128 + (n & 127)) * VTP + 1024] = v;
        } else {
          Kb[((size_t)b * 1025 + 1024) * D_ + n] = v;
        }
      }
    }
  }
}

// --------------------------------------- 256x256 BK=64 4-phase pipelined GEMM
// Per K-tile: 4 quadrant phases {A0B0, A0B1, A1B0, A1B1}, each = entry
// vmcnt(4)+barrier -> 0-12 ds_read_b128 -> stage ONE half-tile of T+1
// (2 gloads) -> lgkmcnt(0) -> 16 MFMA (setprio). Halves staged in order
// Ah0,Bh0,Bh1,Ah1; counted waits keep 4-6 loads in flight (never 0).
// Wave (wm,wn): A rows wm*64+[0,64) in each A-half; B cols wn*32+[0,32) in
// each B-half. acc[hA][mf][nf] with nf=(hB*2+nfq).
template<int FUSED>
__global__ __launch_bounds__(512, 2) void gemm8_kernel(
    const unsigned short* __restrict__ A, const unsigned short* __restrict__ Bw,
    const float* __restrict__ b0v, const float* __restrict__ b1v, const float* __restrict__ b2v,
    void* __restrict__ O0, void* __restrict__ O1, void* __restrict__ O2,
    const int* __restrict__ rowmap, float qalpha, int nbt, int matfix) {
  __shared__ __align__(16) unsigned short lds[2][2][2][8192];  // [buf][mat][half][128x64]
  int tid = threadIdx.x, lane = tid & 63, w = tid >> 6;
  int g = lane >> 4, l15 = lane & 15;
  int wm = w >> 2, wn = w & 3;

  int bid = blockIdx.x;
  int xcd = bid & 7, j = bid >> 3;          // grid = 8 * (4 * nbt)
  int mb = xcd * 4 + j / nbt, nb = j % nbt;
  int m0 = mb * 256, n0 = nb * 256;

  f32x4 acc[2][4][4] = {};

  // staging constants: half = 1024 chunks of 16B over 512 thr x 2 loads
  int c0 = tid, c1 = tid + 512;
  int r0 = c0 >> 3, s0 = (c0 & 7) ^ (r0 & 7);
  int r1 = c1 >> 3, s1 = (c1 & 7) ^ (r1 & 7);
  int dst0 = (w * 64) * 8;          // wave-uniform dest (+lane*16B by HW)
  int dst1 = (w * 64 + 512) * 8;

#define STAGE(MAT, HH, BUF, kt) {                                                 \
    const unsigned short* sp_ = (MAT) ? Bw : A;                                   \
    int gb_ = (MAT) ? n0 : m0;                                                    \
    gload_lds16(sp_ + (size_t)(gb_ + (HH)*128 + r0) * D_ + (kt)*64 + s0*8,        \
                &lds[BUF][MAT][HH][dst0]);                                        \
    gload_lds16(sp_ + (size_t)(gb_ + (HH)*128 + r1) * D_ + (kt)*64 + s1*8,        \
                &lds[BUF][MAT][HH][dst1]);                                        \
  }

  short8 a_[4][2], bb0[2][2], bb1[2][2];
#define RD_A(HH, BUF) { _Pragma("unroll")                                         \
    for (int mf_ = 0; mf_ < 4; ++mf_) {                                           \
      int rr_ = wm * 64 + mf_ * 16 + l15;                                         \
      _Pragma("unroll")                                                           \
      for (int ks_ = 0; ks_ < 2; ++ks_)                                           \
        a_[mf_][ks_] = *(const short8*)(&lds[BUF][0][HH][rr_ * 64 + ((ks_*4+g)^(rr_&7))*8]); } }
#define RD_B(DST, HH, BUF) { _Pragma("unroll")                                    \
    for (int nf_ = 0; nf_ < 2; ++nf_) {                                           \
      int rr_ = wn * 32 + nf_ * 16 + l15;                                         \
      _Pragma("unroll")                                                           \
      for (int ks_ = 0; ks_ < 2; ++ks_)                                           \
        DST[nf_][ks_] = *(const short8*)(&lds[BUF][1][HH][rr_ * 64 + ((ks_*4+g)^(rr_&7))*8]); } }
#define MF8(HA, NB, BSRC) { _Pragma("unroll")                                     \
    for (int mf_ = 0; mf_ < 4; ++mf_)                                             \
      _Pragma("unroll")                                                           \
      for (int nf_ = 0; nf_ < 2; ++nf_)                                           \
        _Pragma("unroll")                                                         \
        for (int ks_ = 0; ks_ < 2; ++ks_)                                         \
          acc[HA][mf_][(NB)+nf_] = __builtin_amdgcn_mfma_f32_16x16x32_bf16(       \
              a_[mf_][ks_], BSRC[nf_][ks_], acc[HA][mf_][(NB)+nf_], 0, 0, 0); }

  // prologue: tile 0's 4 halves, in consumption-retirement order
  STAGE(0, 0, 0, 0); STAGE(1, 0, 0, 0); STAGE(1, 1, 0, 0); STAGE(0, 1, 0, 0);

  for (int T = 0; T < 32; ++T) {
    int BUF = T & 1;
    bool more = (T + 1 < 32);
    // ---- P1: A0 x B0 ----
    asm volatile("s_waitcnt vmcnt(4)" ::: "memory");   // Ah0+Bh0 landed
    __builtin_amdgcn_s_barrier();
    RD_A(0, BUF); RD_B(bb0, 0, BUF);
    if (more) STAGE(0, 0, BUF ^ 1, T + 1);
    asm volatile("s_waitcnt lgkmcnt(0)" ::: "memory");
    __builtin_amdgcn_sched_barrier(0);
    __builtin_amdgcn_s_setprio(1); MF8(0, 0, bb0); __builtin_amdgcn_s_setprio(0);
    // ---- P2: A0 x B1 ----
    if (more) asm volatile("s_waitcnt vmcnt(4)" ::: "memory");  // Bh1 landed
    else      asm volatile("s_waitcnt vmcnt(2)" ::: "memory");
    __builtin_amdgcn_s_barrier();
    RD_B(bb1, 1, BUF);
    if (more) STAGE(1, 0, BUF ^ 1, T + 1);
    asm volatile("s_waitcnt lgkmcnt(0)" ::: "memory");
    __builtin_amdgcn_sched_barrier(0);
    __builtin_amdgcn_s_setprio(1); MF8(0, 2, bb1); __builtin_amdgcn_s_setprio(0);
    // ---- P3: A1 x B0 ----
    if (more) asm volatile("s_waitcnt vmcnt(4)" ::: "memory");  // Ah1 landed
    else      asm volatile("s_waitcnt vmcnt(0)" ::: "memory");
    __builtin_amdgcn_s_barrier();
    RD_A(1, BUF);
    if (more) STAGE(1, 1, BUF ^ 1, T + 1);
    asm volatile("s_waitcnt lgkmcnt(0)" ::: "memory");
    __builtin_amdgcn_sched_barrier(0);
    __builtin_amdgcn_s_setprio(1); MF8(1, 0, bb0); __builtin_amdgcn_s_setprio(0);
    // ---- P4: A1 x B1 (no reads, no vmcnt) ----
    __builtin_amdgcn_s_barrier();
    if (more) STAGE(0, 1, BUF ^ 1, T + 1);
    __builtin_amdgcn_s_setprio(1); MF8(1, 2, bb1); __builtin_amdgcn_s_setprio(0);
  }
#undef MF8
#undef RD_B
#undef RD_A
#undef STAGE

  int mat = 0;
  const float* bias = b0v;
  float alpha = 1.0f;
  int n0l = n0;
  if (FUSED) {
    mat = (matfix >= 0) ? matfix : (n0 >> 11);
    bias = (mat == 0) ? b0v : ((mat == 1) ? b1v : b2v);
    alpha = (mat == 0) ? qalpha : 1.0f;
    n0l = n0 & 2047;
  }

#pragma unroll
  for (int hA = 0; hA < 2; ++hA) {
#pragma unroll
    for (int mf = 0; mf < 4; ++mf) {
#pragma unroll
      for (int nf = 0; nf < 4; ++nf) {
        int nn = n0l + (nf >> 1) * 128 + wn * 32 + (nf & 1) * 16 + l15;
        float bvv = bias[nn];
        int m = m0 + hA * 128 + wm * 64 + mf * 16 + g * 4;
        if (FUSED) {
          if (mat == 2) {                      // V -> transposed Vt
            int bb = m >> 10, tok = m & 1023;
            size_t base = (((size_t)bb * 16 + (nn >> 7)) * 128 + (nn & 127)) * VTP + tok;
            uint2 u;
            u.x = f2bf(acc[hA][mf][nf][0] + bvv) | ((unsigned)f2bf(acc[hA][mf][nf][1] + bvv) << 16);
            u.y = f2bf(acc[hA][mf][nf][2] + bvv) | ((unsigned)f2bf(acc[hA][mf][nf][3] + bvv) << 16);
            *(uint2*)((unsigned short*)O2 + base) = u;
          } else {
            unsigned short* out = (mat == 0) ? (unsigned short*)O0 : (unsigned short*)O1;
#pragma unroll
            for (int r = 0; r < 4; ++r) {
              float v = (acc[hA][mf][nf][r] + bvv) * alpha;
              int mm = m + r;
              int row = (mat == 1) ? mm + (mm >> 10) : mm;
              out[(size_t)row * D_ + nn] = f2bf(v);
            }
          }
        } else {
#pragma unroll
          for (int r = 0; r < 4; ++r) {
            int row = rowmap[m + r];
            ((float*)O0)[(size_t)row * D_ + nn] = acc[hA][mf][nf][r] + bvv;
          }
        }
      }
    }
  }
}

// ----------------------------------------------------------- flash attention
// (unchanged — single-buffer K, early prefetch, fused x->out copy)
__device__ __forceinline__ void stage_k(const unsigned short* Kbase, unsigned short* dst,
                                        int kv0, int w, int lane) {
#pragma unroll
  for (int i = 0; i < 2; ++i) {
    int ib = w * 2 + i;
    int row = ib * 4 + (lane >> 4);
    int sl = (lane & 15) ^ (row & 7);
    int krow = kv0 + row; if (krow > MK_) krow = MK_;
    gload_lds16(Kbase + (size_t)krow * D_ + sl * 8, dst + ib * 512);
  }
}
__device__ __forceinline__ void stage_v(const unsigned short* Vbase, unsigned short* dst,
                                        int kv0, int w, int lane) {
#pragma unroll
  for (int i = 0; i < 2; ++i) {
    int ib = w * 2 + i;
    int row = ib * 8 + (lane >> 3);
    int sl = (lane & 7) ^ (row & 7);
    gload_lds16(Vbase + (size_t)row * VTP + kv0 + sl * 8, dst + ib * 512);
  }
}

#define NF4 16777216   // total float4 in x (8*4096*2048/4)

__global__ __launch_bounds__(512) void attn_kernel(
    const unsigned short* __restrict__ Qb, const unsigned short* __restrict__ Kb,
    const unsigned short* __restrict__ Vt, unsigned short* __restrict__ Ob,
    const float4* __restrict__ xsrc, float4* __restrict__ xdst) {
  int bx = blockIdx.x;
  int gq = bx >> 7;                // 0 = heaviest
  int qi = 7 - gq;
  int bh = bx & 127;
  int b = bh >> 4, h = bh & 15;
  int tid = threadIdx.x, lane = tid & 63, w = tid >> 6;
  int g = lane >> 4, l15 = lane & 15;
  int q0 = qi * 128;
  int nt = 2 * qi + 3;             // causal tiles + register tile

  size_t cpyBase = ((size_t)128 * (18 * gq - gq * gq) + (size_t)(bx & 127) * nt) * 2048;

  __shared__ __align__(16) unsigned short Ks[64 * 128];   // 16 KB, single buffer
  __shared__ __align__(16) unsigned short Vts[128 * 64];  // 16 KB
  __shared__ __align__(16) unsigned short Ps[8][16][72];  // 18 KB

  const unsigned short* Kbase = Kb + (size_t)b * 1025 * D_ + h * HD_;
  const unsigned short* Vbase = Vt + (size_t)bh * 128 * VTP;

  short8 qf[4];
  {
    const unsigned short* qrow = Qb + (size_t)(b * MK_ + q0 + w * 16 + l15) * D_ + h * HD_;
#pragma unroll
    for (int kk = 0; kk < 4; ++kk) qf[kk] = *(const short8*)(qrow + kk * 32 + g * 8);
  }

  f32x4 oacc[8] = {};
  float mrow[4], lrow[4];
#pragma unroll
  for (int r = 0; r < 4; ++r) { mrow[r] = -__builtin_inff(); lrow[r] = 0.f; }

  int qminw = q0 + w * 16;

  stage_k(Kbase, Ks, 0, w, lane);   // prologue: K(0)

  for (int t = 0; t < nt; ++t) {
    int kv0 = (t < nt - 1) ? t * 64 : MK_;

    size_t ci[4];
    float4 cv[4];
    {
      size_t i0 = cpyBase + (size_t)t * 2048 + tid;
#pragma unroll
      for (int jj = 0; jj < 4; ++jj) {
        size_t ix = i0 + jj * 512;
        ci[jj] = ix < NF4 ? ix : (NF4 - 1);
        cv[jj] = xsrc[ci[jj]];
      }
    }

    stage_v(Vbase, Vts, kv0, w, lane);
    if (t == 0) asm volatile("s_waitcnt vmcnt(6)" ::: "memory");
    else        asm volatile("s_waitcnt vmcnt(10)" ::: "memory");
    __builtin_amdgcn_s_barrier();    // barrier 1: Ks(t) visible

    bool active = (t == nt - 1) || (t * 64 <= qminw + 15);
    f32x4 sacc[4] = {};
    if (active) {
      __builtin_amdgcn_s_setprio(1);
#pragma unroll
      for (int kk = 0; kk < 4; ++kk) {
#pragma unroll
        for (int nf = 0; nf < 4; ++nf) {
          int krow = nf * 16 + l15;
          int sw = (kk * 4 + g) ^ (krow & 7);
          short8 kf = *(const short8*)(Ks + krow * 128 + sw * 8);
          sacc[nf] = __builtin_amdgcn_mfma_f32_16x16x32_bf16(qf[kk], kf, sacc[nf], 0, 0, 0);
        }
      }
      __builtin_amdgcn_s_setprio(0);
    }

    __builtin_amdgcn_s_barrier();    // barrier 1.5: all Ks reads in registers
    if (t + 1 < nt) {
      int kv1 = (t + 1 < nt - 1) ? (t + 1) * 64 : MK_;
      stage_k(Kbase, Ks, kv1, w, lane);
    }

    if (active) {
      if (t == nt - 1) {
#pragma unroll
        for (int nf = 0; nf < 4; ++nf) {
          int col = nf * 16 + l15;
          if (col != 0) {
#pragma unroll
            for (int r = 0; r < 4; ++r) sacc[nf][r] = -1e9f;
          }
        }
      } else if (t * 64 + 63 > qminw) {
        int qb = qminw - t * 64 + g * 4;
#pragma unroll
        for (int nf = 0; nf < 4; ++nf) {
          int col = nf * 16 + l15;
#pragma unroll
          for (int r = 0; r < 4; ++r)
            if (col > qb + r) sacc[nf][r] = -1e9f;
        }
      }

      float pm[4]; bool need = false;
#pragma unroll
      for (int r = 0; r < 4; ++r) {
        float mx = fmaxf(fmaxf(sacc[0][r], sacc[1][r]), fmaxf(sacc[2][r], sacc[3][r]));
        mx = fmaxf(mx, __shfl_xor(mx, 1));
        mx = fmaxf(mx, __shfl_xor(mx, 2));
        mx = fmaxf(mx, __shfl_xor(mx, 4));
        mx = fmaxf(mx, __shfl_xor(mx, 8));
        pm[r] = mx;
        need |= (mx > mrow[r] + 8.0f);
      }
      if (__any((int)need)) {
#pragma unroll
        for (int r = 0; r < 4; ++r) {
          float mnew = fmaxf(mrow[r], pm[r]);
          float sf = exp2f(mrow[r] - mnew);
          mrow[r] = mnew;
          lrow[r] *= sf;
#pragma unroll
          for (int i = 0; i < 8; ++i) oacc[i][r] *= sf;
        }
      }
      float rs[4] = {0.f, 0.f, 0.f, 0.f};
#pragma unroll
      for (int nf = 0; nf < 4; ++nf) {
#pragma unroll
        for (int r = 0; r < 4; ++r) {
          float p = exp2f(sacc[nf][r] - mrow[r]);
          sacc[nf][r] = p;
          rs[r] += p;
        }
      }
#pragma unroll
      for (int r = 0; r < 4; ++r) {
        float s = rs[r];
        s += __shfl_xor(s, 1);
        s += __shfl_xor(s, 2);
        s += __shfl_xor(s, 4);
        s += __shfl_xor(s, 8);
        lrow[r] += s;
      }
#pragma unroll
      for (int nf = 0; nf < 4; ++nf)
#pragma unroll
        for (int r = 0; r < 4; ++r)
          Ps[w][g * 4 + r][nf * 16 + l15] = f2bf(sacc[nf][r]);
    }

    if (t + 1 < nt) asm volatile("s_waitcnt vmcnt(2)" ::: "memory");
    else            asm volatile("s_waitcnt vmcnt(0)" ::: "memory");

#pragma unroll
    for (int jj = 0; jj < 4; ++jj) xdst[ci[jj]] = cv[jj];

    __builtin_amdgcn_s_barrier();    // barrier 2: Vts ready

    if (active) {
      __builtin_amdgcn_s_setprio(1);
#pragma unroll
      for (int kk = 0; kk < 2; ++kk) {
        short8 pf = *(const short8*)(&Ps[w][l15][kk * 32 + g * 8]);
#pragma unroll
        for (int nf = 0; nf < 8; ++nf) {
          int vrow = nf * 16 + l15;
          int sw = (kk * 4 + g) ^ (vrow & 7);
          short8 vf = *(const short8*)(Vts + vrow * 64 + sw * 8);
          oacc[nf] = __builtin_amdgcn_mfma_f32_16x16x32_bf16(pf, vf, oacc[nf], 0, 0, 0);
        }
      }
      __builtin_amdgcn_s_setprio(0);
    }
    __builtin_amdgcn_s_barrier();    // barrier 3: protect Vts/Ps overwrite
  }

#pragma unroll
  for (int nf = 0; nf < 8; ++nf) {
#pragma unroll
    for (int r = 0; r < 4; ++r) {
      size_t row = (size_t)b * MK_ + q0 + w * 16 + g * 4 + r;
      Ob[row * D_ + h * HD_ + nf * 16 + l15] = f2bf(oacc[nf][r] / lrow[r]);
    }
  }
}

// ------------------------------------------------------------------- launch
extern "C" void kernel_launch(void* const* d_in, const int* in_sizes, int n_in,
                              void* d_out, int out_size, void* d_ws, size_t ws_size,
                              hipStream_t stream) {
  const float* x    = (const float*)d_in[0];
  const void*  mask = d_in[1];
  const float* reg  = (const float*)d_in[2];
  const float* Wq   = (const float*)d_in[3];
  const float* bq   = (const float*)d_in[4];
  const float* Wk   = (const float*)d_in[5];
  const float* bk   = (const float*)d_in[6];
  const float* Wv   = (const float*)d_in[7];
  const float* bv   = (const float*)d_in[8];
  const float* Wrk  = (const float*)d_in[9];
  const float* brk  = (const float*)d_in[10];
  const float* Wrv  = (const float*)d_in[11];
  const float* brv  = (const float*)d_in[12];
  const float* Wo   = (const float*)d_in[13];
  const float* bo   = (const float*)d_in[14];

  char* ws = (char*)d_ws;
  int* rowmap          = (int*)(ws + 256);               // 32768 B
  char* p = ws + 66048;
  unsigned short* sig = (unsigned short*)p;              p += (size_t)8192 * 2048 * 2;
  unsigned short* Qb  = (unsigned short*)p;              p += (size_t)8192 * 2048 * 2;
  unsigned short* Kb  = (unsigned short*)p;              p += (size_t)8200 * 2048 * 2;
  unsigned short* Vtb = (unsigned short*)p;              p += ((size_t)16384 * VTP + 64) * 2;
  unsigned short* Wbf = (unsigned short*)p;              // 33.6 MB fused / 8.4 MB fallback
  unsigned short* Ob  = sig;  // sig dead after QKV GEMM

  const size_t need_fused = (size_t)(p - ws) + (size_t)8192 * 2048 * 2;
  const bool fused = (ws_size >= need_fused);

  const float qalpha = 0.08838834764831845f * 1.4426950408889634f;
  const size_t per = (size_t)2048 * 2048;

  if (fused) {
    prep1_kernel<<<8200, 256, 0, stream>>>(mask, rowmap, Wq, Wk, Wv, Wo, Wbf);
    prep2_kernel<<<9216, 256, 0, stream>>>(x, rowmap, sig, reg, Wrk, brk, Wrv, brv, Kb, Vtb);
    gemm8_kernel<1><<<768, 512, 0, stream>>>(sig, Wbf, bq, bk, bv, Qb, Kb, Vtb,
                                             nullptr, qalpha, 24, -1);
    attn_kernel<<<1024, 512, 0, stream>>>(Qb, Kb, Vtb, Ob, (const float4*)x, (float4*)d_out);
    gemm8_kernel<0><<<256, 512, 0, stream>>>(Ob, Wbf + 3 * per, bo, nullptr, nullptr,
                                             d_out, nullptr, nullptr, rowmap, 1.0f, 8, -1);
  } else {
    prep1_kernel<<<8, 256, 0, stream>>>(mask, rowmap, Wq, Wk, Wv, Wo, Wbf);
    prep2_kernel<<<9216, 256, 0, stream>>>(x, rowmap, sig, reg, Wrk, brk, Wrv, brv, Kb, Vtb);
    prep1_kernel<<<8200, 256, 0, stream>>>(mask, rowmap, Wq, Wq, Wq, Wq, Wbf);
    gemm8_kernel<1><<<256, 512, 0, stream>>>(sig, Wbf, bq, bk, bv, Qb, Kb, Vtb,
                                             nullptr, qalpha, 8, 0);
    prep1_kernel<<<8200, 256, 0, stream>>>(mask, rowmap, Wk, Wk, Wk, Wk, Wbf);
    gemm8_kernel<1><<<256, 512, 0, stream>>>(sig, Wbf, bq, bk, bv, Qb, Kb, Vtb,
                                             nullptr, qalpha, 8, 1);
    prep1_kernel<<<8200, 256, 0, stream>>>(mask, rowmap, Wv, Wv, Wv, Wv, Wbf);
    gemm8_kernel<1><<<256, 512, 0, stream>>>(sig, Wbf, bq, bk, bv, Qb, Kb, Vtb,
                                             nullptr, qalpha, 8, 2);
    attn_kernel<<<1024, 512, 0, stream>>>(Qb, Kb, Vtb, Ob, (const float4*)x, (float4*)d_out);
    prep1_kernel<<<8200, 256, 0, stream>>>(mask, rowmap, Wo, Wo, Wo, Wo, Wbf);
    gemm8_kernel<0><<<256, 512, 0, stream>>>(Ob, Wbf, bo, nullptr, nullptr,
                                             d_out, nullptr, nullptr, rowmap, 1.0f, 8, -1);
  }
}

// Round 13
// 478.320 us; speedup vs baseline: 1.1132x; 1.0520x over previous
//
#include <hip/hip_runtime.h>
#include <hip/hip_bf16.h>

#define B_  8
#define L_  4096
#define D_  2048
#define H_  16
#define HD_ 128
#define MK_ 1024
#define VTP 1040   // Vt row pitch (k dim, 1025 used + pad)
#define NNS 24576  // non-selected rows total (8 * 3072)

typedef __attribute__((ext_vector_type(8))) short short8;
typedef __attribute__((ext_vector_type(4))) float f32x4;

__device__ inline unsigned short f2bf(float f) {
  unsigned int u = __float_as_uint(f);
  unsigned int r = (u + 0x7fffu + ((u >> 16) & 1u)) >> 16;   // RNE
  return (unsigned short)r;
}

__device__ __forceinline__ void gload_lds16(const void* g, void* l) {
  __builtin_amdgcn_global_load_lds(
      (const __attribute__((address_space(1))) void*)g,
      (__attribute__((address_space(3))) void*)l, 16, 0, 0);
}

// ---------------- prep1: mask-dtype detect + rowmap + nsrow (blocks 0..7) + weight conv
__global__ __launch_bounds__(256) void prep1_kernel(
    const void* __restrict__ maskv, int* __restrict__ rowmap, int* __restrict__ nsrow,
    const float* __restrict__ W0, const float* __restrict__ W1,
    const float* __restrict__ W2, const float* __restrict__ W3,
    unsigned short* __restrict__ Wb) {
  int bid = blockIdx.x;
  int tid = threadIdx.x;
  if (bid < 8) {
    __shared__ int cnt;
    __shared__ int cnts[256];
    const unsigned char* m8 = (const unsigned char*)maskv;
    if (tid == 0) cnt = 0;
    __syncthreads();
    int local = 0;
    for (int i = tid; i < B_ * L_; i += 256) local += (m8[i] != 0);
    atomicAdd(&cnt, local);
    __syncthreads();
    int cv = cnt;
    int t = 0;
    if (cv == B_ * MK_)      t = 0; // u8 bool
    else if (cv == 2 * MK_)  t = 1; // i32
    else if (cv == 4 * MK_)  t = 2; // f32
    int b = bid;
    unsigned char loc[16];
    int c = 0;
    for (int j = 0; j < 16; ++j) {
      int pos = tid * 16 + j;
      int mv;
      if (t == 1)      mv = ((const int*)maskv)[b * L_ + pos] != 0;
      else if (t == 2) mv = ((const float*)maskv)[b * L_ + pos] != 0.0f;
      else             mv = m8[b * L_ + pos] != 0;
      loc[j] = (unsigned char)mv; c += mv;
    }
    cnts[tid] = c;
    __syncthreads();
    for (int off = 1; off < 256; off <<= 1) {
      int v = (tid >= off) ? cnts[tid - off] : 0;
      __syncthreads();
      cnts[tid] += v;
      __syncthreads();
    }
    int rank = cnts[tid] - c;
    for (int j = 0; j < 16; ++j) {
      int pos = tid * 16 + j;
      if (loc[j]) {
        if (rank < MK_) rowmap[b * MK_ + rank] = b * L_ + pos;
        ++rank;
      } else {
        int ns = pos - rank;              // rank = #selected before pos
        if (ns < 3072) nsrow[b * 3072 + ns] = b * L_ + pos;
      }
    }
  } else {
    const size_t per = (size_t)D_ * D_;
    int cb = bid - 8;
    int slab = cb >> 11;
    const float* W = (slab == 0) ? W0 : (slab == 1) ? W1 : (slab == 2) ? W2 : W3;
    size_t i = ((size_t)(cb & 2047) * 256 + tid) * 8;
    float4 a = *(const float4*)(W + i);
    float4 b4 = *(const float4*)(W + i + 4);
    uint4 o;
    o.x = f2bf(a.x)  | ((unsigned)f2bf(a.y)  << 16);
    o.y = f2bf(a.z)  | ((unsigned)f2bf(a.w)  << 16);
    o.z = f2bf(b4.x) | ((unsigned)f2bf(b4.y) << 16);
    o.w = f2bf(b4.z) | ((unsigned)f2bf(b4.w) << 16);
    *(uint4*)(Wb + slab * per + i) = o;
  }
}

// ---------------- prep2: gather+convert sig (blocks 0..8191) + register K/V rows
__global__ __launch_bounds__(256) void prep2_kernel(
    const float* __restrict__ x, const int* __restrict__ rowmap,
    unsigned short* __restrict__ sig,
    const float* __restrict__ reg, const float* __restrict__ Wrk, const float* __restrict__ brk,
    const float* __restrict__ Wrv, const float* __restrict__ brv,
    unsigned short* __restrict__ Kb, unsigned short* __restrict__ Vt) {
  int bid = blockIdx.x;
  int tid = threadIdx.x;
  if (bid < 8192) {
    int row = bid;
    const float* src = x + (size_t)rowmap[row] * D_;
    unsigned short* dst = sig + (size_t)row * D_;
    float4 a = ((const float4*)src)[tid * 2];
    float4 b4 = ((const float4*)src)[tid * 2 + 1];
    uint4 o;
    o.x = f2bf(a.x)  | ((unsigned)f2bf(a.y)  << 16);
    o.y = f2bf(a.z)  | ((unsigned)f2bf(a.w)  << 16);
    o.z = f2bf(b4.x) | ((unsigned)f2bf(b4.y) << 16);
    o.w = f2bf(b4.z) | ((unsigned)f2bf(b4.w) << 16);
    *(uint4*)(dst + tid * 8) = o;
  } else {
    int gw = ((bid - 8192) * 256 + tid) >> 6;  // 4096 waves
    int lane = tid & 63;
    int mat = gw >> 11;
    int n = gw & 2047;
    const float* W = mat ? Wrv : Wrk;
    const float* wrow = W + (size_t)n * D_;
    float s[8] = {};
    for (int j = 0; j < 8; ++j) {
      int e = j * 256 + lane * 4;
      float4 wv = *(const float4*)(wrow + e);
#pragma unroll
      for (int b = 0; b < 8; ++b) {
        float4 rv = *(const float4*)(reg + (size_t)b * D_ + e);
        s[b] += wv.x * rv.x + wv.y * rv.y + wv.z * rv.z + wv.w * rv.w;
      }
    }
#pragma unroll
    for (int off = 32; off; off >>= 1)
#pragma unroll
      for (int b = 0; b < 8; ++b) s[b] += __shfl_down(s[b], off);
    if (lane == 0) {
      float bias = (mat ? brv : brk)[n];
#pragma unroll
      for (int b = 0; b < 8; ++b) {
        unsigned short v = f2bf(s[b] + bias);
        if (mat) {
          Vt[(((size_t)b * 16 + (n >> 7)) * 128 + (n & 127)) * VTP + 1024] = v;
        } else {
          Kb[((size_t)b * 1025 + 1024) * D_ + n] = v;
        }
      }
    }
  }
}

// --------------------------------------- 256x256 BK=64 4-phase pipelined GEMM
// (frozen — LDS-bandwidth-bound at ~47-49% MfmaUtil across 4 schedule variants)
template<int FUSED>
__global__ __launch_bounds__(512, 2) void gemm8_kernel(
    const unsigned short* __restrict__ A, const unsigned short* __restrict__ Bw,
    const float* __restrict__ b0v, const float* __restrict__ b1v, const float* __restrict__ b2v,
    void* __restrict__ O0, void* __restrict__ O1, void* __restrict__ O2,
    const int* __restrict__ rowmap, float qalpha, int nbt, int matfix) {
  __shared__ __align__(16) unsigned short lds[2][2][2][8192];  // [buf][mat][half][128x64]
  int tid = threadIdx.x, lane = tid & 63, w = tid >> 6;
  int g = lane >> 4, l15 = lane & 15;
  int wm = w >> 2, wn = w & 3;

  int bid = blockIdx.x;
  int xcd = bid & 7, j = bid >> 3;          // grid = 8 * (4 * nbt)
  int mb = xcd * 4 + j / nbt, nb = j % nbt;
  int m0 = mb * 256, n0 = nb * 256;

  f32x4 acc[2][4][4] = {};

  int c0 = tid, c1 = tid + 512;
  int r0 = c0 >> 3, s0 = (c0 & 7) ^ (r0 & 7);
  int r1 = c1 >> 3, s1 = (c1 & 7) ^ (r1 & 7);
  int dst0 = (w * 64) * 8;
  int dst1 = (w * 64 + 512) * 8;

#define STAGE(MAT, HH, BUF, kt) {                                                 \
    const unsigned short* sp_ = (MAT) ? Bw : A;                                   \
    int gb_ = (MAT) ? n0 : m0;                                                    \
    gload_lds16(sp_ + (size_t)(gb_ + (HH)*128 + r0) * D_ + (kt)*64 + s0*8,        \
                &lds[BUF][MAT][HH][dst0]);                                        \
    gload_lds16(sp_ + (size_t)(gb_ + (HH)*128 + r1) * D_ + (kt)*64 + s1*8,        \
                &lds[BUF][MAT][HH][dst1]);                                        \
  }

  short8 a_[4][2], bb0[2][2], bb1[2][2];
#define RD_A(HH, BUF) { _Pragma("unroll")                                         \
    for (int mf_ = 0; mf_ < 4; ++mf_) {                                           \
      int rr_ = wm * 64 + mf_ * 16 + l15;                                         \
      _Pragma("unroll")                                                           \
      for (int ks_ = 0; ks_ < 2; ++ks_)                                           \
        a_[mf_][ks_] = *(const short8*)(&lds[BUF][0][HH][rr_ * 64 + ((ks_*4+g)^(rr_&7))*8]); } }
#define RD_B(DST, HH, BUF) { _Pragma("unroll")                                    \
    for (int nf_ = 0; nf_ < 2; ++nf_) {                                           \
      int rr_ = wn * 32 + nf_ * 16 + l15;                                         \
      _Pragma("unroll")                                                           \
      for (int ks_ = 0; ks_ < 2; ++ks_)                                           \
        DST[nf_][ks_] = *(const short8*)(&lds[BUF][1][HH][rr_ * 64 + ((ks_*4+g)^(rr_&7))*8]); } }
#define MF8(HA, NB, BSRC) { _Pragma("unroll")                                     \
    for (int mf_ = 0; mf_ < 4; ++mf_)                                             \
      _Pragma("unroll")                                                           \
      for (int nf_ = 0; nf_ < 2; ++nf_)                                           \
        _Pragma("unroll")                                                         \
        for (int ks_ = 0; ks_ < 2; ++ks_)                                         \
          acc[HA][mf_][(NB)+nf_] = __builtin_amdgcn_mfma_f32_16x16x32_bf16(       \
              a_[mf_][ks_], BSRC[nf_][ks_], acc[HA][mf_][(NB)+nf_], 0, 0, 0); }

  STAGE(0, 0, 0, 0); STAGE(1, 0, 0, 0); STAGE(1, 1, 0, 0); STAGE(0, 1, 0, 0);

  for (int T = 0; T < 32; ++T) {
    int BUF = T & 1;
    bool more = (T + 1 < 32);
    // ---- P1: A0 x B0 ----
    asm volatile("s_waitcnt vmcnt(4)" ::: "memory");
    __builtin_amdgcn_s_barrier();
    RD_A(0, BUF); RD_B(bb0, 0, BUF);
    if (more) STAGE(0, 0, BUF ^ 1, T + 1);
    asm volatile("s_waitcnt lgkmcnt(0)" ::: "memory");
    __builtin_amdgcn_sched_barrier(0);
    __builtin_amdgcn_s_setprio(1); MF8(0, 0, bb0); __builtin_amdgcn_s_setprio(0);
    // ---- P2: A0 x B1 ----
    if (more) asm volatile("s_waitcnt vmcnt(4)" ::: "memory");
    else      asm volatile("s_waitcnt vmcnt(2)" ::: "memory");
    __builtin_amdgcn_s_barrier();
    RD_B(bb1, 1, BUF);
    if (more) STAGE(1, 0, BUF ^ 1, T + 1);
    asm volatile("s_waitcnt lgkmcnt(0)" ::: "memory");
    __builtin_amdgcn_sched_barrier(0);
    __builtin_amdgcn_s_setprio(1); MF8(0, 2, bb1); __builtin_amdgcn_s_setprio(0);
    // ---- P3: A1 x B0 ----
    if (more) asm volatile("s_waitcnt vmcnt(4)" ::: "memory");
    else      asm volatile("s_waitcnt vmcnt(0)" ::: "memory");
    __builtin_amdgcn_s_barrier();
    RD_A(1, BUF);
    if (more) STAGE(1, 1, BUF ^ 1, T + 1);
    asm volatile("s_waitcnt lgkmcnt(0)" ::: "memory");
    __builtin_amdgcn_sched_barrier(0);
    __builtin_amdgcn_s_setprio(1); MF8(1, 0, bb0); __builtin_amdgcn_s_setprio(0);
    // ---- P4: A1 x B1 ----
    __builtin_amdgcn_s_barrier();
    if (more) STAGE(0, 1, BUF ^ 1, T + 1);
    __builtin_amdgcn_s_setprio(1); MF8(1, 2, bb1); __builtin_amdgcn_s_setprio(0);
  }
#undef MF8
#undef RD_B
#undef RD_A
#undef STAGE

  int mat = 0;
  const float* bias = b0v;
  float alpha = 1.0f;
  int n0l = n0;
  if (FUSED) {
    mat = (matfix >= 0) ? matfix : (n0 >> 11);
    bias = (mat == 0) ? b0v : ((mat == 1) ? b1v : b2v);
    alpha = (mat == 0) ? qalpha : 1.0f;
    n0l = n0 & 2047;
  }

#pragma unroll
  for (int hA = 0; hA < 2; ++hA) {
#pragma unroll
    for (int mf = 0; mf < 4; ++mf) {
#pragma unroll
      for (int nf = 0; nf < 4; ++nf) {
        int nn = n0l + (nf >> 1) * 128 + wn * 32 + (nf & 1) * 16 + l15;
        float bvv = bias[nn];
        int m = m0 + hA * 128 + wm * 64 + mf * 16 + g * 4;
        if (FUSED) {
          if (mat == 2) {                      // V -> transposed Vt
            int bb = m >> 10, tok = m & 1023;
            size_t base = (((size_t)bb * 16 + (nn >> 7)) * 128 + (nn & 127)) * VTP + tok;
            uint2 u;
            u.x = f2bf(acc[hA][mf][nf][0] + bvv) | ((unsigned)f2bf(acc[hA][mf][nf][1] + bvv) << 16);
            u.y = f2bf(acc[hA][mf][nf][2] + bvv) | ((unsigned)f2bf(acc[hA][mf][nf][3] + bvv) << 16);
            *(uint2*)((unsigned short*)O2 + base) = u;
          } else {
            unsigned short* out = (mat == 0) ? (unsigned short*)O0 : (unsigned short*)O1;
#pragma unroll
            for (int r = 0; r < 4; ++r) {
              float v = (acc[hA][mf][nf][r] + bvv) * alpha;
              int mm = m + r;
              int row = (mat == 1) ? mm + (mm >> 10) : mm;
              out[(size_t)row * D_ + nn] = f2bf(v);
            }
          }
        } else {
#pragma unroll
          for (int r = 0; r < 4; ++r) {
            int row = rowmap[m + r];
            ((float*)O0)[(size_t)row * D_ + nn] = acc[hA][mf][nf][r] + bvv;
          }
        }
      }
    }
  }
}

// ----------------------------------------------------------- flash attention
// Copy now covers ONLY non-selected rows via nsrow list (3 rows/tile-step,
// list slice preloaded into LDS so index reads never touch vmcnt).
// vmcnt ledger (issue order per iter: K(t)[2] oldest -> stores(t-1)[3] ->
// copy loads(t)[3] -> V(t)[2]):
//   head wait: retire K(t) -> vmcnt(8)  (t=0: 5)
//   mid  wait: retire stores+copies+V; K(t+1)[2] stays -> vmcnt(2) (last: 0)
__device__ __forceinline__ void stage_k(const unsigned short* Kbase, unsigned short* dst,
                                        int kv0, int w, int lane) {
#pragma unroll
  for (int i = 0; i < 2; ++i) {
    int ib = w * 2 + i;
    int row = ib * 4 + (lane >> 4);
    int sl = (lane & 15) ^ (row & 7);
    int krow = kv0 + row; if (krow > MK_) krow = MK_;
    gload_lds16(Kbase + (size_t)krow * D_ + sl * 8, dst + ib * 512);
  }
}
__device__ __forceinline__ void stage_v(const unsigned short* Vbase, unsigned short* dst,
                                        int kv0, int w, int lane) {
#pragma unroll
  for (int i = 0; i < 2; ++i) {
    int ib = w * 2 + i;
    int row = ib * 8 + (lane >> 3);
    int sl = (lane & 7) ^ (row & 7);
    gload_lds16(Vbase + (size_t)row * VTP + kv0 + sl * 8, dst + ib * 512);
  }
}

__global__ __launch_bounds__(512) void attn_kernel(
    const unsigned short* __restrict__ Qb, const unsigned short* __restrict__ Kb,
    const unsigned short* __restrict__ Vt, unsigned short* __restrict__ Ob,
    const float4* __restrict__ xsrc, float4* __restrict__ xdst,
    const int* __restrict__ nsrow) {
  int bx = blockIdx.x;
  int gq = bx >> 7;                // 0 = heaviest
  int qi = 7 - gq;
  int bh = bx & 127;
  int b = bh >> 4, h = bh & 15;
  int tid = threadIdx.x, lane = tid & 63, w = tid >> 6;
  int g = lane >> 4, l15 = lane & 15;
  int q0 = qi * 128;
  int nt = 2 * qi + 3;             // causal tiles + register tile

  __shared__ __align__(16) unsigned short Ks[64 * 128];   // 16 KB, single buffer
  __shared__ __align__(16) unsigned short Vts[128 * 64];  // 16 KB
  __shared__ __align__(16) unsigned short Ps[8][16][72];  // 18 KB
  __shared__ int lds_ns[64];                               // copy-row list slice

  const unsigned short* Kbase = Kb + (size_t)b * 1025 * D_ + h * HD_;
  const unsigned short* Vbase = Vt + (size_t)bh * 128 * VTP;

  short8 qf[4];
  {
    const unsigned short* qrow = Qb + (size_t)(b * MK_ + q0 + w * 16 + l15) * D_ + h * HD_;
#pragma unroll
    for (int kk = 0; kk < 4; ++kk) qf[kk] = *(const short8*)(qrow + kk * 32 + g * 8);
  }

  f32x4 oacc[8] = {};
  float mrow[4], lrow[4];
#pragma unroll
  for (int r = 0; r < 4; ++r) { mrow[r] = -__builtin_inff(); lrow[r] = 0.f; }

  int qminw = q0 + w * 16;

  // preload this block's non-selected row list slice (nrows = 3*nt <= 51)
  {
    int nrows = nt * 3;
    int listBase = 384 * (18 * gq - gq * gq) + (bx & 127) * nrows;
    if (tid < nrows) {
      int li = listBase + tid; if (li > NNS - 1) li = NNS - 1;
      lds_ns[tid] = nsrow[li];
    }
  }
  stage_k(Kbase, Ks, 0, w, lane);   // prologue: K(0)
  asm volatile("s_waitcnt lgkmcnt(0)" ::: "memory");
  __builtin_amdgcn_s_barrier();      // lds_ns visible to all waves

  for (int t = 0; t < nt; ++t) {
    int kv0 = (t < nt - 1) ? t * 64 : MK_;

    // ---- copy loads: 3 non-selected rows, 1 float4/thread/row ----
    int cr0 = lds_ns[t * 3], cr1 = lds_ns[t * 3 + 1], cr2 = lds_ns[t * 3 + 2];
    float4 cv0 = xsrc[(size_t)cr0 * 512 + tid];
    float4 cv1 = xsrc[(size_t)cr1 * 512 + tid];
    float4 cv2 = xsrc[(size_t)cr2 * 512 + tid];

    stage_v(Vbase, Vts, kv0, w, lane);
    // head wait: retire ONLY K(t); stores/copies/V stay in flight
    if (t == 0) asm volatile("s_waitcnt vmcnt(5)" ::: "memory");
    else        asm volatile("s_waitcnt vmcnt(8)" ::: "memory");
    __builtin_amdgcn_s_barrier();    // barrier 1: Ks(t) visible

    bool active = (t == nt - 1) || (t * 64 <= qminw + 15);
    f32x4 sacc[4] = {};
    if (active) {
      __builtin_amdgcn_s_setprio(1);
#pragma unroll
      for (int kk = 0; kk < 4; ++kk) {
#pragma unroll
        for (int nf = 0; nf < 4; ++nf) {
          int krow = nf * 16 + l15;
          int sw = (kk * 4 + g) ^ (krow & 7);
          short8 kf = *(const short8*)(Ks + krow * 128 + sw * 8);
          sacc[nf] = __builtin_amdgcn_mfma_f32_16x16x32_bf16(qf[kk], kf, sacc[nf], 0, 0, 0);
        }
      }
      __builtin_amdgcn_s_setprio(0);
    }

    __builtin_amdgcn_s_barrier();    // barrier 1.5: all Ks reads in registers
    if (t + 1 < nt) {
      int kv1 = (t + 1 < nt - 1) ? (t + 1) * 64 : MK_;
      stage_k(Kbase, Ks, kv1, w, lane);
    }

    if (active) {
      if (t == nt - 1) {
#pragma unroll
        for (int nf = 0; nf < 4; ++nf) {
          int col = nf * 16 + l15;
          if (col != 0) {
#pragma unroll
            for (int r = 0; r < 4; ++r) sacc[nf][r] = -1e9f;
          }
        }
      } else if (t * 64 + 63 > qminw) {
        int qb = qminw - t * 64 + g * 4;
#pragma unroll
        for (int nf = 0; nf < 4; ++nf) {
          int col = nf * 16 + l15;
#pragma unroll
          for (int r = 0; r < 4; ++r)
            if (col > qb + r) sacc[nf][r] = -1e9f;
        }
      }

      float pm[4]; bool need = false;
#pragma unroll
      for (int r = 0; r < 4; ++r) {
        float mx = fmaxf(fmaxf(sacc[0][r], sacc[1][r]), fmaxf(sacc[2][r], sacc[3][r]));
        mx = fmaxf(mx, __shfl_xor(mx, 1));
        mx = fmaxf(mx, __shfl_xor(mx, 2));
        mx = fmaxf(mx, __shfl_xor(mx, 4));
        mx = fmaxf(mx, __shfl_xor(mx, 8));
        pm[r] = mx;
        need |= (mx > mrow[r] + 8.0f);
      }
      if (__any((int)need)) {
#pragma unroll
        for (int r = 0; r < 4; ++r) {
          float mnew = fmaxf(mrow[r], pm[r]);
          float sf = exp2f(mrow[r] - mnew);
          mrow[r] = mnew;
          lrow[r] *= sf;
#pragma unroll
          for (int i = 0; i < 8; ++i) oacc[i][r] *= sf;
        }
      }
      float rs[4] = {0.f, 0.f, 0.f, 0.f};
#pragma unroll
      for (int nf = 0; nf < 4; ++nf) {
#pragma unroll
        for (int r = 0; r < 4; ++r) {
          float p = exp2f(sacc[nf][r] - mrow[r]);
          sacc[nf][r] = p;
          rs[r] += p;
        }
      }
#pragma unroll
      for (int r = 0; r < 4; ++r) {
        float s = rs[r];
        s += __shfl_xor(s, 1);
        s += __shfl_xor(s, 2);
        s += __shfl_xor(s, 4);
        s += __shfl_xor(s, 8);
        lrow[r] += s;
      }
#pragma unroll
      for (int nf = 0; nf < 4; ++nf)
#pragma unroll
        for (int r = 0; r < 4; ++r)
          Ps[w][g * 4 + r][nf * 16 + l15] = f2bf(sacc[nf][r]);
    }

    // mid wait: retire stores(t-1)+copies(t)+V(t); keep K(t+1) in flight
    if (t + 1 < nt) asm volatile("s_waitcnt vmcnt(2)" ::: "memory");
    else            asm volatile("s_waitcnt vmcnt(0)" ::: "memory");

    // ---- copy stores (loads retired by the wait above) ----
    xdst[(size_t)cr0 * 512 + tid] = cv0;
    xdst[(size_t)cr1 * 512 + tid] = cv1;
    xdst[(size_t)cr2 * 512 + tid] = cv2;

    __builtin_amdgcn_s_barrier();    // barrier 2: Vts ready

    if (active) {
      __builtin_amdgcn_s_setprio(1);
#pragma unroll
      for (int kk = 0; kk < 2; ++kk) {
        short8 pf = *(const short8*)(&Ps[w][l15][kk * 32 + g * 8]);
#pragma unroll
        for (int nf = 0; nf < 8; ++nf) {
          int vrow = nf * 16 + l15;
          int sw = (kk * 4 + g) ^ (vrow & 7);
          short8 vf = *(const short8*)(Vts + vrow * 64 + sw * 8);
          oacc[nf] = __builtin_amdgcn_mfma_f32_16x16x32_bf16(pf, vf, oacc[nf], 0, 0, 0);
        }
      }
      __builtin_amdgcn_s_setprio(0);
    }
    __builtin_amdgcn_s_barrier();    // barrier 3: protect Vts/Ps overwrite
  }

#pragma unroll
  for (int nf = 0; nf < 8; ++nf) {
#pragma unroll
    for (int r = 0; r < 4; ++r) {
      size_t row = (size_t)b * MK_ + q0 + w * 16 + g * 4 + r;
      Ob[row * D_ + h * HD_ + nf * 16 + l15] = f2bf(oacc[nf][r] / lrow[r]);
    }
  }
}

// ------------------------------------------------------------------- launch
extern "C" void kernel_launch(void* const* d_in, const int* in_sizes, int n_in,
                              void* d_out, int out_size, void* d_ws, size_t ws_size,
                              hipStream_t stream) {
  const float* x    = (const float*)d_in[0];
  const void*  mask = d_in[1];
  const float* reg  = (const float*)d_in[2];
  const float* Wq   = (const float*)d_in[3];
  const float* bq   = (const float*)d_in[4];
  const float* Wk   = (const float*)d_in[5];
  const float* bk   = (const float*)d_in[6];
  const float* Wv   = (const float*)d_in[7];
  const float* bv   = (const float*)d_in[8];
  const float* Wrk  = (const float*)d_in[9];
  const float* brk  = (const float*)d_in[10];
  const float* Wrv  = (const float*)d_in[11];
  const float* brv  = (const float*)d_in[12];
  const float* Wo   = (const float*)d_in[13];
  const float* bo   = (const float*)d_in[14];

  char* ws = (char*)d_ws;
  int* rowmap = (int*)(ws + 256);      // 32 KB  (ends 33024)
  int* nsrow  = (int*)(ws + 33024);    // 96 KB  (ends 131328)
  char* p = ws + 131328;
  unsigned short* sig = (unsigned short*)p;              p += (size_t)8192 * 2048 * 2;
  unsigned short* Qb  = (unsigned short*)p;              p += (size_t)8192 * 2048 * 2;
  unsigned short* Kb  = (unsigned short*)p;              p += (size_t)8200 * 2048 * 2;
  unsigned short* Vtb = (unsigned short*)p;              p += ((size_t)16384 * VTP + 64) * 2;
  unsigned short* Wbf = (unsigned short*)p;              // 33.6 MB fused / 8.4 MB fallback
  unsigned short* Ob  = sig;  // sig dead after QKV GEMM

  const size_t need_fused = (size_t)(p - ws) + (size_t)8192 * 2048 * 2;
  const bool fused = (ws_size >= need_fused);

  const float qalpha = 0.08838834764831845f * 1.4426950408889634f;
  const size_t per = (size_t)2048 * 2048;

  if (fused) {
    prep1_kernel<<<8200, 256, 0, stream>>>(mask, rowmap, nsrow, Wq, Wk, Wv, Wo, Wbf);
    prep2_kernel<<<9216, 256, 0, stream>>>(x, rowmap, sig, reg, Wrk, brk, Wrv, brv, Kb, Vtb);
    gemm8_kernel<1><<<768, 512, 0, stream>>>(sig, Wbf, bq, bk, bv, Qb, Kb, Vtb,
                                             nullptr, qalpha, 24, -1);
    attn_kernel<<<1024, 512, 0, stream>>>(Qb, Kb, Vtb, Ob, (const float4*)x, (float4*)d_out, nsrow);
    gemm8_kernel<0><<<256, 512, 0, stream>>>(Ob, Wbf + 3 * per, bo, nullptr, nullptr,
                                             d_out, nullptr, nullptr, rowmap, 1.0f, 8, -1);
  } else {
    prep1_kernel<<<8, 256, 0, stream>>>(mask, rowmap, nsrow, Wq, Wk, Wv, Wo, Wbf);
    prep2_kernel<<<9216, 256, 0, stream>>>(x, rowmap, sig, reg, Wrk, brk, Wrv, brv, Kb, Vtb);
    prep1_kernel<<<8200, 256, 0, stream>>>(mask, rowmap, nsrow, Wq, Wq, Wq, Wq, Wbf);
    gemm8_kernel<1><<<256, 512, 0, stream>>>(sig, Wbf, bq, bk, bv, Qb, Kb, Vtb,
                                             nullptr, qalpha, 8, 0);
    prep1_kernel<<<8200, 256, 0, stream>>>(mask, rowmap, nsrow, Wk, Wk, Wk, Wk, Wbf);
    gemm8_kernel<1><<<256, 512, 0, stream>>>(sig, Wbf, bq, bk, bv, Qb, Kb, Vtb,
                                             nullptr, qalpha, 8, 1);
    prep1_kernel<<<8200, 256, 0, stream>>>(mask, rowmap, nsrow, Wv, Wv, Wv, Wv, Wbf);
    gemm8_kernel<1><<<256, 512, 0, stream>>>(sig, Wbf, bq, bk, bv, Qb, Kb, Vtb,
                                             nullptr, qalpha, 8, 2);
    attn_kernel<<<1024, 512, 0, stream>>>(Qb, Kb, Vtb, Ob, (const float4*)x, (float4*)d_out, nsrow);
    prep1_kernel<<<8200, 256, 0, stream>>>(mask, rowmap, nsrow, Wo, Wo, Wo, Wo, Wbf);
    gemm8_kernel<0><<<256, 512, 0, stream>>>(Ob, Wbf, bo, nullptr, nullptr,
                                             d_out, nullptr, nullptr, rowmap, 1.0f, 8, -1);
  }
}